// Round 10
// baseline (601.243 us; speedup 1.0000x reference)
//
#include <hip/hip_runtime.h>
#include <hip/hip_bf16.h>

#define N_NODES 10000
#define N_EDGES 160000
#define TPW_PLANE ((size_t)N_EDGES * 128)
#define EB 32   /* edges per block (dual m-tile) */
#define NB 16   /* nodes per block in node kernels */

typedef short v8s __attribute__((ext_vector_type(8)));
typedef float v4f __attribute__((ext_vector_type(4)));

__device__ __forceinline__ float bf2f(ushort u) {
    union { unsigned i; float f; } x; x.i = ((unsigned)u) << 16; return x.f;
}
__device__ __forceinline__ float fin(float x) {
    return (x == x) ? fminf(fmaxf(x, -1e30f), 1e30f) : 0.f;
}
__device__ __forceinline__ ushort f2bf(float f) {
    union { unsigned i; float f; } x; x.f = fin(f);
    unsigned i = x.i;
    unsigned r = (i + 0x7fffu + ((i >> 16) & 1u)) >> 16;
    return (ushort)r;
}
// HW packed f32x2 -> bf16x2 (RNE), one VALU op instead of ~10.
__device__ __forceinline__ unsigned cvt_pk_bf16(float lo, float hi) {
    unsigned r;
    asm("v_cvt_pk_bf16_f32 %0, %1, %2" : "=v"(r) : "v"(lo), "v"(hi));
    return r;
}
// Raw v_rcp_f32 (~1 ulp) — replaces the 7-op exact-div sequence in silu;
// bf16 output rounding absorbs the error.
__device__ __forceinline__ float fast_rcp(float x) {
    float r;
    asm("v_rcp_f32 %0, %1" : "=v"(r) : "v"(x));
    return r;
}
__device__ __forceinline__ float silu(float x) {
    return x * fast_rcp(1.f + __expf(-x));
}

#define INV_C 0.08838834764831845f      /* 1/sqrt(128) */
#define S_MLP1 0.08574929257125442f     /* 1/sqrt(136) */
#define S_MLP 0.0625f                   /* 1/16 */
#define INV_SQRT3 0.5773502691896258f
#define OUT_SCALE 0.00390625f           /* (1/sqrt(256))/16 */

#define MFMA __builtin_amdgcn_mfma_f32_16x16x32_bf16

// ---------------------------------------------------------------------------
// Weight pre-pack: fp32 -> bf16 MFMA B-fragment order.
// wl1 packed as TWO K=128 halves (top / bottom) for the Z-factorization.
// ---------------------------------------------------------------------------
__global__ __launch_bounds__(256) void pack_kernel(
    const float* __restrict__ w1, const float* __restrict__ w2,
    const float* __restrict__ w3, const float* __restrict__ w4,
    const float* __restrict__ wl0, const float* __restrict__ wl1,
    ushort* __restrict__ w1p, ushort* __restrict__ w2p,
    ushort* __restrict__ w3p, ushort* __restrict__ w4p,
    ushort* __restrict__ wl0p, ushort* __restrict__ wl1p)
{
    int idx = blockIdx.x * 256 + threadIdx.x;
    const float* W; ushort* D; int KT, Kreal, Nn, id, koff = 0;
    if (idx < 40960)       { W = w1;  D = w1p;  KT = 5; Kreal = 136; Nn = 256; id = idx; }
    else if (idx < 106496) { W = w2;  D = w2p;  KT = 8; Kreal = 256; Nn = 256; id = idx - 40960; }
    else if (idx < 172032) { W = w3;  D = w3p;  KT = 8; Kreal = 256; Nn = 256; id = idx - 106496; }
    else if (idx < 303104) { W = w4;  D = w4p;  KT = 8; Kreal = 256; Nn = 512; id = idx - 172032; }
    else if (idx < 335872) { W = wl0; D = wl0p; KT = 8; Kreal = 256; Nn = 128; id = idx - 303104; }
    else if (idx < 352256) { W = wl1; D = wl1p;         KT = 4; Kreal = 128; Nn = 128; id = idx - 335872; }
    else                   { W = wl1; D = wl1p + 16384; KT = 4; Kreal = 128; Nn = 128; id = idx - 352256; koff = 128; }
    int j = id & 7, lane = (id >> 3) & 63, tt = id >> 9;
    int kt = tt % KT, nt = tt / KT;
    int k = kt * 32 + ((lane >> 4) << 3) + j;
    int nn = nt * 16 + (lane & 15);
    D[id] = (k < Kreal) ? f2bf(W[(k + koff) * Nn + nn]) : (ushort)0;
}

// ---------------------------------------------------------------------------
// Node up/down projections, 16 nodes/block. u1 stored PLANAR.
// ---------------------------------------------------------------------------
__global__ __launch_bounds__(256) void node_uud_kernel(
    const float* __restrict__ nf,
    const float* __restrict__ Wu0, const float* __restrict__ Wu1,
    const float* __restrict__ Wd,
    ushort* __restrict__ u0, ushort* __restrict__ u1,
    ushort* __restrict__ down)
{
    __shared__ float x[NB * 512];
    int t = threadIdx.x;
    int n0 = blockIdx.x * NB;
    {
        const float4* src = (const float4*)(nf + (size_t)n0 * 512);
        float4* dst = (float4*)x;
        for (int i = t; i < NB * 128; i += 256) dst[i] = src[i];
    }
    __syncthreads();
    int v = t & 127, g = t >> 7;
    {
        float acc[8] = {0.f,0.f,0.f,0.f,0.f,0.f,0.f,0.f};
        for (int u = 0; u < 128; ++u) {
            float wv = Wu0[u * 128 + v];
#pragma unroll
            for (int j = 0; j < 8; ++j) acc[j] += x[(g * 8 + j) * 512 + u] * wv;
        }
#pragma unroll
        for (int j = 0; j < 8; ++j)
            u0[(size_t)(n0 + g * 8 + j) * 128 + v] = f2bf(acc[j] * INV_C);
    }
    for (int i = 0; i < 3; ++i) {
        float acc[8] = {0.f,0.f,0.f,0.f,0.f,0.f,0.f,0.f};
        for (int u = 0; u < 128; ++u) {
            float wv = Wu1[u * 128 + v];
#pragma unroll
            for (int j = 0; j < 8; ++j)
                acc[j] += x[(g * 8 + j) * 512 + 128 + u * 3 + i] * wv;
        }
#pragma unroll
        for (int j = 0; j < 8; ++j)
            u1[(size_t)(n0 + g * 8 + j) * 384 + i * 128 + v] = f2bf(acc[j] * INV_C);
    }
    {
        int vd = t & 63, gd = t >> 6;
        float acc[4] = {0.f,0.f,0.f,0.f};
        for (int u = 0; u < 128; ++u) {
            float wv = Wd[u * 64 + vd];
#pragma unroll
            for (int j = 0; j < 4; ++j) acc[j] += x[(gd * 4 + j) * 512 + u] * wv;
        }
#pragma unroll
        for (int j = 0; j < 4; ++j)
            down[(size_t)(n0 + gd * 4 + j) * 64 + vd] = f2bf(acc[j] * INV_C);
    }
}

// ---------------------------------------------------------------------------
// Skip connection, 16 nodes/block (runs LAST). The x1-part (v*3+i layout)
// is staged in LDS and written out as coalesced float4 (was stride-3 scatter).
// ---------------------------------------------------------------------------
__global__ __launch_bounds__(256) void node_sc_kernel(
    const float* __restrict__ nf,
    const float* __restrict__ Ws0, const float* __restrict__ Ws1,
    float* __restrict__ out_sc)
{
    __shared__ float x[NB * 512];
    __shared__ float xs[NB * 384];
    int t = threadIdx.x;
    int n0 = blockIdx.x * NB;
    {
        const float4* src = (const float4*)(nf + (size_t)n0 * 512);
        float4* dst = (float4*)x;
        for (int i = t; i < NB * 128; i += 256) dst[i] = src[i];
    }
    __syncthreads();
    int v = t & 127, g = t >> 7;
    {
        float acc[8] = {0.f,0.f,0.f,0.f,0.f,0.f,0.f,0.f};
        for (int u = 0; u < 128; ++u) {
            float wv = Ws0[u * 128 + v];
#pragma unroll
            for (int j = 0; j < 8; ++j) acc[j] += x[(g * 8 + j) * 512 + u] * wv;
        }
#pragma unroll
        for (int j = 0; j < 8; ++j)
            out_sc[(size_t)(n0 + g * 8 + j) * 512 + v] = fin(acc[j] * INV_C);
    }
    for (int i = 0; i < 3; ++i) {
        float acc[8] = {0.f,0.f,0.f,0.f,0.f,0.f,0.f,0.f};
        for (int u = 0; u < 128; ++u) {
            float wv = Ws1[u * 128 + v];
#pragma unroll
            for (int j = 0; j < 8; ++j)
                acc[j] += x[(g * 8 + j) * 512 + 128 + u * 3 + i] * wv;
        }
#pragma unroll
        for (int j = 0; j < 8; ++j)
            xs[(g * 8 + j) * 384 + v * 3 + i] = fin(acc[j] * INV_C);
    }
    __syncthreads();
    for (int i = t; i < NB * 96; i += 256) {
        int nd = i / 96, k = i - nd * 96;
        *(float4*)&out_sc[(size_t)(n0 + nd) * 512 + 128 + k * 4] =
            *(const float4*)&xs[nd * 384 + k * 4];
    }
}

// ---------------------------------------------------------------------------
// CSR build (receiver-sorted edge list).
// ---------------------------------------------------------------------------
__global__ __launch_bounds__(256) void hist_kernel(const int* __restrict__ eidx, int* __restrict__ counts)
{
    int e = blockIdx.x * 256 + threadIdx.x;
    int r = eidx[N_EDGES + e];
    if (r < 0) r = 0; if (r >= N_NODES) r = N_NODES - 1;
    atomicAdd(&counts[r], 1);
}

__global__ __launch_bounds__(1024) void scan_kernel(const int* __restrict__ counts, int* __restrict__ offs)
{
    __shared__ int buf[1024];
    __shared__ int base_s;
    int t = threadIdx.x;
    if (t == 0) { base_s = 0; offs[0] = 0; }
    __syncthreads();
    for (int chunk = 0; chunk < (N_NODES + 1023) / 1024; ++chunk) {
        int i = chunk * 1024 + t;
        int vv = (i < N_NODES) ? counts[i] : 0;
        buf[t] = vv;
        __syncthreads();
        for (int off = 1; off < 1024; off <<= 1) {
            int xv = (t >= off) ? buf[t - off] : 0;
            __syncthreads();
            buf[t] += xv;
            __syncthreads();
        }
        int incl = buf[t];
        int base = base_s;
        __syncthreads();
        if (i < N_NODES) offs[i + 1] = base + incl;
        if (t == 1023) base_s = base + incl;
        __syncthreads();
    }
}

__global__ __launch_bounds__(256) void fill_kernel(
    const int* __restrict__ eidx, const int* __restrict__ offs,
    int* __restrict__ cnt2, int* __restrict__ esort)
{
    int e = blockIdx.x * 256 + threadIdx.x;
    int r = eidx[N_EDGES + e];
    if (r < 0) r = 0; if (r >= N_NODES) r = N_NODES - 1;
    int k = atomicAdd(&cnt2[r], 1);
    int pos = offs[r] + k;
    if (pos < 0) pos = 0; if (pos >= N_EDGES) pos = N_EDGES - 1;
    esort[pos] = e;
}

// ---------------------------------------------------------------------------
// Dual-m-tile hidden-layer GEMM: 32 edges (two 16-row m-tiles) x 256 out.
// Each B-fragment loaded once serves both m-tiles (weight L2 traffic halved).
// ---------------------------------------------------------------------------
#define H_STRIDE 264

template <int KT, bool SILU>
__device__ __forceinline__ void gemm_layer(
    const ushort* __restrict__ wpack, const ushort* srcLDS, int srcStride,
    ushort* dstLDS, float scale)
{
    int t = threadIdx.x;
    int w = t >> 6, l = t & 63;
    int lrow = l & 15, q = l >> 4;

    for (int p = 0; p < 2; ++p) {
        int nt0 = w * 4 + 2 * p, nt1 = nt0 + 1;
        v4f a00 = {0.f,0.f,0.f,0.f}, a01 = {0.f,0.f,0.f,0.f};
        v4f a10 = {0.f,0.f,0.f,0.f}, a11 = {0.f,0.f,0.f,0.f};
#pragma unroll
        for (int kt = 0; kt < KT; ++kt) {
            v8s b0 = *(const v8s*)&wpack[(size_t)(nt0 * KT + kt) * 512 + l * 8];
            v8s b1 = *(const v8s*)&wpack[(size_t)(nt1 * KT + kt) * 512 + l * 8];
            v8s x0 = *(const v8s*)&srcLDS[lrow * srcStride + kt * 32 + q * 8];
            v8s x1 = *(const v8s*)&srcLDS[(16 + lrow) * srcStride + kt * 32 + q * 8];
            a00 = MFMA(x0, b0, a00, 0, 0, 0);
            a01 = MFMA(x0, b1, a01, 0, 0, 0);
            a10 = MFMA(x1, b0, a10, 0, 0, 0);
            a11 = MFMA(x1, b1, a11, 0, 0, 0);
        }
#pragma unroll
        for (int r = 0; r < 4; ++r) {
            float x00 = a00[r] * scale, x01 = a01[r] * scale;
            float x10 = a10[r] * scale, x11 = a11[r] * scale;
            if (SILU) {
                x00 = silu(x00); x01 = silu(x01);
                x10 = silu(x10); x11 = silu(x11);
            }
            int row0 = q * 4 + r, row1 = row0 + 16;
            unsigned p0 = cvt_pk_bf16(x00, x01);
            dstLDS[row0 * H_STRIDE + nt0 * 16 + lrow] = (ushort)p0;
            dstLDS[row0 * H_STRIDE + nt1 * 16 + lrow] = (ushort)(p0 >> 16);
            unsigned p1 = cvt_pk_bf16(x10, x11);
            dstLDS[row1 * H_STRIDE + nt0 * 16 + lrow] = (ushort)p1;
            dstLDS[row1 * H_STRIDE + nt1 * 16 + lrow] = (ushort)(p1 >> 16);
        }
    }
    __syncthreads();
}

// Output GEMM [32x256]@[256x128], dual-m. Path A writes tpw by SORTED slot
// (e0+row == position in esort) so gather reads contiguous rows.
template <bool ATOMIC>
__device__ __forceinline__ void gemm_out(
    const ushort* __restrict__ wpack, const ushort* srcLDS,
    const int* s_rcv, float* __restrict__ out, ushort* __restrict__ tpw,
    int e0, int cofs)
{
    int t = threadIdx.x;
    int w = t >> 6, l = t & 63;
    int lrow = l & 15, q = l >> 4;
    ushort* plane = tpw + (size_t)cofs * TPW_PLANE;
    int nt0 = w * 2, nt1 = nt0 + 1;
    v4f a00 = {0.f,0.f,0.f,0.f}, a01 = {0.f,0.f,0.f,0.f};
    v4f a10 = {0.f,0.f,0.f,0.f}, a11 = {0.f,0.f,0.f,0.f};
#pragma unroll
    for (int kt = 0; kt < 8; ++kt) {
        v8s b0 = *(const v8s*)&wpack[(size_t)(nt0 * 8 + kt) * 512 + l * 8];
        v8s b1 = *(const v8s*)&wpack[(size_t)(nt1 * 8 + kt) * 512 + l * 8];
        v8s x0 = *(const v8s*)&srcLDS[lrow * H_STRIDE + kt * 32 + q * 8];
        v8s x1 = *(const v8s*)&srcLDS[(16 + lrow) * H_STRIDE + kt * 32 + q * 8];
        a00 = MFMA(x0, b0, a00, 0, 0, 0);
        a01 = MFMA(x0, b1, a01, 0, 0, 0);
        a10 = MFMA(x1, b0, a10, 0, 0, 0);
        a11 = MFMA(x1, b1, a11, 0, 0, 0);
    }
    int col0 = nt0 * 16 + lrow, col1 = col0 + 16;
#pragma unroll
    for (int r = 0; r < 4; ++r) {
        int row0 = q * 4 + r, row1 = row0 + 16;
        if constexpr (ATOMIC) {
            int rcv0 = s_rcv[row0], rcv1 = s_rcv[row1];
            atomicAdd(&out[(size_t)rcv0 * 512 + col0 * 4 + cofs], fin(a00[r] * OUT_SCALE));
            atomicAdd(&out[(size_t)rcv0 * 512 + col1 * 4 + cofs], fin(a01[r] * OUT_SCALE));
            atomicAdd(&out[(size_t)rcv1 * 512 + col0 * 4 + cofs], fin(a10[r] * OUT_SCALE));
            atomicAdd(&out[(size_t)rcv1 * 512 + col1 * 4 + cofs], fin(a11[r] * OUT_SCALE));
        } else {
            size_t base0 = (size_t)(e0 + row0) * 128;
            unsigned p0 = cvt_pk_bf16(a00[r] * OUT_SCALE, a01[r] * OUT_SCALE);
            plane[base0 + col0] = (ushort)p0;
            plane[base0 + col1] = (ushort)(p0 >> 16);
            size_t base1 = (size_t)(e0 + row1) * 128;
            unsigned p1 = cvt_pk_bf16(a10[r] * OUT_SCALE, a11[r] * OUT_SCALE);
            plane[base1 + col0] = (ushort)p1;
            plane[base1 + col1] = (ushort)(p1 >> 16);
        }
    }
}

// ---------------------------------------------------------------------------
// Edge-parallel fused kernel: EB=32, 4 waves, dual m-tile, RECEIVER-SORTED
// edge order (esort, path A): tpw slot = sorted position -> gather reads
// contiguous rows with zero indirection. The CSR is needed anyway, so this
// ordering is free (unlike R7's dual-CSR sender sort).
// __launch_bounds__(256,3): VGPR budget ~85, no spill (gfx950 law 256/minw).
// ---------------------------------------------------------------------------
template <bool ATOMIC>
__global__ __launch_bounds__(256, 3) void edge_msg_kernel(
    const int* __restrict__ eidx, const int* __restrict__ esort,
    const float* __restrict__ ef, const float* __restrict__ ea,
    const ushort* __restrict__ down,
    const ushort* __restrict__ u0, const ushort* __restrict__ u1,
    const ushort* __restrict__ w1p, const ushort* __restrict__ w2p,
    const ushort* __restrict__ w3p, const ushort* __restrict__ w4p,
    const ushort* __restrict__ wl0p, const ushort* __restrict__ wl1p,
    float* __restrict__ out_msg, ushort* __restrict__ tpw)
{
    __shared__ __align__(16) ushort s_hA[EB * H_STRIDE];
    __shared__ __align__(16) ushort s_hB[EB * H_STRIDE];
    __shared__ __align__(16) ushort s_q[EB * H_STRIDE];   // q1 cols [0,128), q2 cols [128,256)
    __shared__ int s_snd[EB];
    __shared__ int s_rcv[EB];
    __shared__ int s_eid[EB];
    __shared__ float s_y[EB][4];

    int t = threadIdx.x;
    int e0 = blockIdx.x * EB;

    if (t < EB) {
        int e;
        if constexpr (ATOMIC) {
            e = e0 + t;
        } else {
            e = esort[e0 + t];
            if (e < 0) e = 0; if (e >= N_EDGES) e = N_EDGES - 1;
        }
        s_eid[t] = e;
        int s = eidx[e];
        int r = eidx[N_EDGES + e];
        if (s < 0) s = 0; if (s >= N_NODES) s = N_NODES - 1;
        if (r < 0) r = 0; if (r >= N_NODES) r = N_NODES - 1;
        s_snd[t] = s; s_rcv[t] = r;
        s_y[t][0] = fin(ea[(size_t)e * 4 + 0]);
        s_y[t][1] = fin(ea[(size_t)e * 4 + 1]);
        s_y[t][2] = fin(ea[(size_t)e * 4 + 2]);
        s_y[t][3] = fin(ea[(size_t)e * 4 + 3]);
    }
    __syncthreads();
    // stage aug into s_hB stride 168 — 8 threads/edge, 21 cols each (8*21=168)
    {
        int e = t >> 3, c0 = (t & 7) * 21;
        int snd = s_snd[e], rcv = s_rcv[e], eid = s_eid[e];
#pragma unroll
        for (int j = 0; j < 21; ++j) {
            int cc = c0 + j;
            ushort vv;
            if (cc < 8)        vv = f2bf(ef[(size_t)eid * 8 + cc]);
            else if (cc < 72)  vv = down[(size_t)snd * 64 + (cc - 8)];
            else if (cc < 136) vv = down[(size_t)rcv * 64 + (cc - 72)];
            else               vv = 0;
            s_hB[e * 168 + cc] = vv;
        }
    }
    __syncthreads();
    gemm_layer<5, true>(w1p, s_hB, 168, s_hA, S_MLP1);       // aug -> hA
    gemm_layer<8, true>(w2p, s_hA, H_STRIDE, s_hB, S_MLP);   // hA  -> hB
    gemm_layer<8, true>(w3p, s_hB, H_STRIDE, s_hA, S_MLP);   // hB  -> hA

    // ---- layer 4 quarters (dual-m, in-loop A reads from hA) ----
    int w = t >> 6, l = t & 63;
    int lrow = l & 15, q = l >> 4;
    int colg0 = w * 32 + lrow, colg1 = colg0 + 16;

    for (int qd = 0; qd < 4; ++qd) {
        int nt0 = qd * 8 + w * 2, nt1 = nt0 + 1;
        v4f a00 = {0.f,0.f,0.f,0.f}, a01 = {0.f,0.f,0.f,0.f};
        v4f a10 = {0.f,0.f,0.f,0.f}, a11 = {0.f,0.f,0.f,0.f};
#pragma unroll
        for (int kt = 0; kt < 8; ++kt) {
            v8s b0 = *(const v8s*)&w4p[(size_t)(nt0 * 8 + kt) * 512 + l * 8];
            v8s b1 = *(const v8s*)&w4p[(size_t)(nt1 * 8 + kt) * 512 + l * 8];
            v8s x0 = *(const v8s*)&s_hA[lrow * H_STRIDE + kt * 32 + q * 8];
            v8s x1 = *(const v8s*)&s_hA[(16 + lrow) * H_STRIDE + kt * 32 + q * 8];
            a00 = MFMA(x0, b0, a00, 0, 0, 0);
            a01 = MFMA(x0, b1, a01, 0, 0, 0);
            a10 = MFMA(x1, b0, a10, 0, 0, 0);
            a11 = MFMA(x1, b1, a11, 0, 0, 0);
        }
#pragma unroll
        for (int r = 0; r < 4; ++r) {
#pragma unroll
            for (int m = 0; m < 2; ++m) {
                int row = m * 16 + q * 4 + r;
                float v0 = (m == 0 ? a00[r] : a10[r]) * S_MLP;
                float v1 = (m == 0 ? a01[r] : a11[r]) * S_MLP;
                int snd = s_snd[row];
                if (qd == 0) {
                    float y0 = s_y[row][0];
                    float ua = bf2f(u0[(size_t)snd * 128 + colg0]);
                    float ub = bf2f(u0[(size_t)snd * 128 + colg1]);
                    unsigned pk = cvt_pk_bf16(v0 * ua * y0, v1 * ub * y0);
                    s_hB[row * H_STRIDE + colg0] = (ushort)pk;
                    s_hB[row * H_STRIDE + colg1] = (ushort)(pk >> 16);
                } else if (qd == 1) {
                    float ua = bf2f(u0[(size_t)snd * 128 + colg0]);
                    float ub = bf2f(u0[(size_t)snd * 128 + colg1]);
                    unsigned pk = cvt_pk_bf16(v0 * ua, v1 * ub);
                    s_q[row * H_STRIDE + colg0] = (ushort)pk;
                    s_q[row * H_STRIDE + colg1] = (ushort)(pk >> 16);
                } else if (qd == 2) {
                    unsigned pk = cvt_pk_bf16(v0, v1);
                    s_q[row * H_STRIDE + 128 + colg0] = (ushort)pk;
                    s_q[row * H_STRIDE + 128 + colg1] = (ushort)(pk >> 16);
                } else {
                    size_t ub_ = (size_t)snd * 384;
                    float d0 = bf2f(u1[ub_ + colg0])       * s_y[row][1]
                             + bf2f(u1[ub_ + 128 + colg0]) * s_y[row][2]
                             + bf2f(u1[ub_ + 256 + colg0]) * s_y[row][3];
                    float d1 = bf2f(u1[ub_ + colg1])       * s_y[row][1]
                             + bf2f(u1[ub_ + 128 + colg1]) * s_y[row][2]
                             + bf2f(u1[ub_ + 256 + colg1]) * s_y[row][3];
                    unsigned pk = cvt_pk_bf16(v0 * d0 * INV_SQRT3, v1 * d1 * INV_SQRT3);
                    s_hB[row * H_STRIDE + 128 + colg0] = (ushort)pk;
                    s_hB[row * H_STRIDE + 128 + colg1] = (ushort)(pk >> 16);
                }
            }
        }
    }
    __syncthreads();

    gemm_out<ATOMIC>(wl0p, s_hB, s_rcv, out_msg, tpw, e0, 0);
    __syncthreads();

    // ---- wl1 with Z-factorization (dual-m) ----
    const ushort* wl1t = wl1p;            // rows [0,128)  of W_lin1, KT=4
    const ushort* wl1b = wl1p + 16384;    // rows [128,256) of W_lin1, KT=4
    int ntz0 = w * 2, ntz1 = ntz0 + 1;
    int colz0 = ntz0 * 16 + lrow, colz1 = colz0 + 16;

    // Z = q1 @ wl1_top, held in regs across the i-loop
    v4f z00 = {0.f,0.f,0.f,0.f}, z01 = {0.f,0.f,0.f,0.f};
    v4f z10 = {0.f,0.f,0.f,0.f}, z11 = {0.f,0.f,0.f,0.f};
#pragma unroll
    for (int kt = 0; kt < 4; ++kt) {
        v8s b0 = *(const v8s*)&wl1t[(size_t)(ntz0 * 4 + kt) * 512 + l * 8];
        v8s b1 = *(const v8s*)&wl1t[(size_t)(ntz1 * 4 + kt) * 512 + l * 8];
        v8s x0 = *(const v8s*)&s_q[lrow * H_STRIDE + kt * 32 + q * 8];
        v8s x1 = *(const v8s*)&s_q[(16 + lrow) * H_STRIDE + kt * 32 + q * 8];
        z00 = MFMA(x0, b0, z00, 0, 0, 0);
        z01 = MFMA(x0, b1, z01, 0, 0, 0);
        z10 = MFMA(x1, b0, z10, 0, 0, 0);
        z11 = MFMA(x1, b1, z11, 0, 0, 0);
    }

    for (int i = 0; i < 3; ++i) {
        // rebuild q2*u1_i*y0 into s_hB cols [0,128), 2-wide packed
#pragma unroll
        for (int it = 0; it < 8; ++it) {
            int idx = t + it * 256;
            int e = idx >> 6, kp = (idx & 63) << 1;
            unsigned uq = *(const unsigned*)&s_q[e * H_STRIDE + 128 + kp];
            unsigned uu = *(const unsigned*)&u1[(size_t)s_snd[e] * 384 + i * 128 + kp];
            float y0 = s_y[e][0];
            float lo = bf2f((ushort)uq) * bf2f((ushort)uu) * y0;
            float hi = bf2f((ushort)(uq >> 16)) * bf2f((ushort)(uu >> 16)) * y0;
            *(unsigned*)&s_hB[e * H_STRIDE + kp] = cvt_pk_bf16(lo, hi);
        }
        __syncthreads();
        // P_i = rebuilt @ wl1_bot; combine out = y_{1+i}*Z + P_i
        v4f p00 = {0.f,0.f,0.f,0.f}, p01 = {0.f,0.f,0.f,0.f};
        v4f p10 = {0.f,0.f,0.f,0.f}, p11 = {0.f,0.f,0.f,0.f};
#pragma unroll
        for (int kt = 0; kt < 4; ++kt) {
            v8s b0 = *(const v8s*)&wl1b[(size_t)(ntz0 * 4 + kt) * 512 + l * 8];
            v8s b1 = *(const v8s*)&wl1b[(size_t)(ntz1 * 4 + kt) * 512 + l * 8];
            v8s x0 = *(const v8s*)&s_hB[lrow * H_STRIDE + kt * 32 + q * 8];
            v8s x1 = *(const v8s*)&s_hB[(16 + lrow) * H_STRIDE + kt * 32 + q * 8];
            p00 = MFMA(x0, b0, p00, 0, 0, 0);
            p01 = MFMA(x0, b1, p01, 0, 0, 0);
            p10 = MFMA(x1, b0, p10, 0, 0, 0);
            p11 = MFMA(x1, b1, p11, 0, 0, 0);
        }
        ushort* plane = tpw + (size_t)(1 + i) * TPW_PLANE;
#pragma unroll
        for (int r = 0; r < 4; ++r) {
            int row0 = q * 4 + r, row1 = row0 + 16;
            float yi0 = s_y[row0][1 + i], yi1 = s_y[row1][1 + i];
            float v00 = (yi0 * z00[r] + p00[r]) * OUT_SCALE;
            float v01 = (yi0 * z01[r] + p01[r]) * OUT_SCALE;
            float v10 = (yi1 * z10[r] + p10[r]) * OUT_SCALE;
            float v11 = (yi1 * z11[r] + p11[r]) * OUT_SCALE;
            if constexpr (ATOMIC) {
                int rcv0 = s_rcv[row0], rcv1 = s_rcv[row1];
                atomicAdd(&out_msg[(size_t)rcv0 * 512 + colz0 * 4 + 1 + i], fin(v00));
                atomicAdd(&out_msg[(size_t)rcv0 * 512 + colz1 * 4 + 1 + i], fin(v01));
                atomicAdd(&out_msg[(size_t)rcv1 * 512 + colz0 * 4 + 1 + i], fin(v10));
                atomicAdd(&out_msg[(size_t)rcv1 * 512 + colz1 * 4 + 1 + i], fin(v11));
            } else {
                size_t base0 = (size_t)(e0 + row0) * 128;
                unsigned pk0 = cvt_pk_bf16(v00, v01);
                plane[base0 + colz0] = (ushort)pk0;
                plane[base0 + colz1] = (ushort)(pk0 >> 16);
                size_t base1 = (size_t)(e0 + row1) * 128;
                unsigned pk1 = cvt_pk_bf16(v10, v11);
                plane[base1 + colz0] = (ushort)pk1;
                plane[base1 + colz1] = (ushort)(pk1 >> 16);
            }
        }
        __syncthreads();
    }
}

// ---------------------------------------------------------------------------
// Path A gather — tpw indexed by SORTED position: each node reads CONTIGUOUS
// rows [beg,end), no esort indirection. u32 reads: wave p covers plane p,
// lane c covers cols {2c,2c+1} -> 256 B/wave/load, fully coalesced.
// ---------------------------------------------------------------------------
__global__ __launch_bounds__(256) void gather_kernel(
    const int* __restrict__ offs,
    const ushort* __restrict__ tpw, float* __restrict__ out_msg)
{
    int n = blockIdx.x, t = threadIdx.x;
    int beg = offs[n];
    if (beg < 0) beg = 0; if (beg > N_EDGES) beg = N_EDGES;
    int end = offs[n + 1];
    if (end < beg) end = beg; if (end > N_EDGES) end = N_EDGES;
    int c = t & 63;        // column pair index: cols 2c, 2c+1
    int p = t >> 6;        // plane 0..3
    const unsigned* src = (const unsigned*)(tpw + (size_t)p * TPW_PLANE) + c;
    float a0 = 0.f, a1 = 0.f;
    for (int j = beg; j < end; ++j) {
        unsigned v = src[(size_t)j * 64];
        a0 += bf2f((ushort)v);
        a1 += bf2f((ushort)(v >> 16));
    }
    out_msg[(size_t)n * 512 + (2 * c) * 4 + p] = fin(a0);
    out_msg[(size_t)n * 512 + (2 * c + 1) * 4 + p] = fin(a1);
}

// ---------------------------------------------------------------------------
extern "C" void kernel_launch(void* const* d_in, const int* in_sizes, int n_in,
                              void* d_out, int out_size, void* d_ws, size_t ws_size,
                              hipStream_t stream)
{
    const float* node_feats = (const float*)d_in[1];
    const float* edge_attrs = (const float*)d_in[2];
    const float* edge_feats = (const float*)d_in[3];
    const int*   edge_index = (const int*)d_in[4];
    const float* W_up0  = (const float*)d_in[5];
    const float* W_up1  = (const float*)d_in[6];
    const float* W_down = (const float*)d_in[7];
    const float* mlp_w1 = (const float*)d_in[8];
    const float* mlp_w2 = (const float*)d_in[9];
    const float* mlp_w3 = (const float*)d_in[10];
    const float* mlp_w4 = (const float*)d_in[11];
    const float* W_lin0 = (const float*)d_in[12];
    const float* W_lin1 = (const float*)d_in[13];
    const float* W_skip0 = (const float*)d_in[14];
    const float* W_skip1 = (const float*)d_in[15];

    // d_out fp32: [message: 20,480,000 B][sc: 20,480,000 B]
    char* S = (char*)d_out + 20480000;   // sc half = scratch until node_sc

    ushort* u0    = (ushort*)(S + 0);           //  2,560,000 B
    ushort* down  = (ushort*)(S + 2560000);     //  1,280,000 B
    ushort* u1    = (ushort*)(S + 3840000);     //  7,680,000 B (planar [n][i][128])
    ushort* w1p   = (ushort*)(S + 11520000);    //     81,920 B
    ushort* w2p   = (ushort*)(S + 11601920);    //    131,072 B
    ushort* w3p   = (ushort*)(S + 11732992);    //    131,072 B
    ushort* w4p   = (ushort*)(S + 11864064);    //    262,144 B
    ushort* wl0p  = (ushort*)(S + 12126208);    //     65,536 B
    ushort* wl1p  = (ushort*)(S + 12191744);    //     65,536 B (top 32K + bottom 32K)
    int*    offs  = (int*)(S + 12257280);       //     40,032 B
    int*    esort = (int*)(S + 12297312);       //    640,000 B
    int*    counts= (int*)(S + 12937312);       //     40,000 B
    int*    cnt2  = (int*)(S + 12977312);       //     40,000 B -> 13,017,312

    float* out_msg = (float*)d_out;
    float* out_sc  = (float*)d_out + (size_t)N_NODES * 512;

    const size_t TPW_BYTES = (size_t)N_EDGES * 512 * 2;   // 163,840,000
    bool bigws = (ws_size >= TPW_BYTES) && (d_ws != nullptr);
    ushort* tpw = (ushort*)d_ws;

    pack_kernel<<<1440, 256, 0, stream>>>(mlp_w1, mlp_w2, mlp_w3, mlp_w4, W_lin0, W_lin1,
                                          w1p, w2p, w3p, w4p, wl0p, wl1p);
    node_uud_kernel<<<N_NODES / NB, 256, 0, stream>>>(node_feats, W_up0, W_up1, W_down, u0, u1, down);

    if (bigws) {
        hipMemsetAsync(counts, 0, 80000, stream);
        hist_kernel<<<N_EDGES / 256, 256, 0, stream>>>(edge_index, counts);
        scan_kernel<<<1, 1024, 0, stream>>>(counts, offs);
        fill_kernel<<<N_EDGES / 256, 256, 0, stream>>>(edge_index, offs, cnt2, esort);
        edge_msg_kernel<false><<<N_EDGES / EB, 256, 0, stream>>>(edge_index, esort,
            edge_feats, edge_attrs,
            down, u0, u1, w1p, w2p, w3p, w4p, wl0p, wl1p, out_msg, tpw);
        gather_kernel<<<N_NODES, 256, 0, stream>>>(offs, tpw, out_msg);
    } else {
        hipMemsetAsync(out_msg, 0, 20480000, stream);
        edge_msg_kernel<true><<<N_EDGES / EB, 256, 0, stream>>>(edge_index, esort,
            edge_feats, edge_attrs,
            down, u0, u1, w1p, w2p, w3p, w4p, wl0p, wl1p, out_msg, tpw);
    }
    node_sc_kernel<<<N_NODES / NB, 256, 0, stream>>>(node_feats, W_skip0, W_skip1, out_sc);
}

// Round 11
// 552.146 us; speedup vs baseline: 1.0889x; 1.0889x over previous
//
#include <hip/hip_runtime.h>
#include <hip/hip_bf16.h>

#define N_NODES 10000
#define N_EDGES 160000
#define EB 32   /* edges per block (dual m-tile) */
#define NB 16   /* nodes per block in node kernels */

typedef short v8s __attribute__((ext_vector_type(8)));
typedef float v4f __attribute__((ext_vector_type(4)));

__device__ __forceinline__ float bf2f(ushort u) {
    union { unsigned i; float f; } x; x.i = ((unsigned)u) << 16; return x.f;
}
__device__ __forceinline__ float fin(float x) {
    return (x == x) ? fminf(fmaxf(x, -1e30f), 1e30f) : 0.f;
}
__device__ __forceinline__ ushort f2bf(float f) {
    union { unsigned i; float f; } x; x.f = fin(f);
    unsigned i = x.i;
    unsigned r = (i + 0x7fffu + ((i >> 16) & 1u)) >> 16;
    return (ushort)r;
}
// HW packed f32x2 -> bf16x2 (RNE), one VALU op instead of ~10.
__device__ __forceinline__ unsigned cvt_pk_bf16(float lo, float hi) {
    unsigned r;
    asm("v_cvt_pk_bf16_f32 %0, %1, %2" : "=v"(r) : "v"(lo), "v"(hi));
    return r;
}
// Raw v_rcp_f32 (~1 ulp) — bf16 output rounding absorbs the error.
__device__ __forceinline__ float fast_rcp(float x) {
    float r;
    asm("v_rcp_f32 %0, %1" : "=v"(r) : "v"(x));
    return r;
}
__device__ __forceinline__ float silu(float x) {
    return x * fast_rcp(1.f + __expf(-x));
}

#define INV_C 0.08838834764831845f      /* 1/sqrt(128) */
#define S_MLP1 0.08574929257125442f     /* 1/sqrt(136) */
#define S_MLP 0.0625f                   /* 1/16 */
#define INV_SQRT3 0.5773502691896258f
#define OUT_SCALE 0.00390625f           /* (1/sqrt(256))/16 */

#define MFMA __builtin_amdgcn_mfma_f32_16x16x32_bf16

// ---------------------------------------------------------------------------
// Weight pre-pack: fp32 -> bf16 MFMA B-fragment order.
// wl1 packed as TWO K=128 halves (top / bottom) for the Z-factorization.
// ---------------------------------------------------------------------------
__global__ __launch_bounds__(256) void pack_kernel(
    const float* __restrict__ w1, const float* __restrict__ w2,
    const float* __restrict__ w3, const float* __restrict__ w4,
    const float* __restrict__ wl0, const float* __restrict__ wl1,
    ushort* __restrict__ w1p, ushort* __restrict__ w2p,
    ushort* __restrict__ w3p, ushort* __restrict__ w4p,
    ushort* __restrict__ wl0p, ushort* __restrict__ wl1p)
{
    int idx = blockIdx.x * 256 + threadIdx.x;
    const float* W; ushort* D; int KT, Kreal, Nn, id, koff = 0;
    if (idx < 40960)       { W = w1;  D = w1p;  KT = 5; Kreal = 136; Nn = 256; id = idx; }
    else if (idx < 106496) { W = w2;  D = w2p;  KT = 8; Kreal = 256; Nn = 256; id = idx - 40960; }
    else if (idx < 172032) { W = w3;  D = w3p;  KT = 8; Kreal = 256; Nn = 256; id = idx - 106496; }
    else if (idx < 303104) { W = w4;  D = w4p;  KT = 8; Kreal = 256; Nn = 512; id = idx - 172032; }
    else if (idx < 335872) { W = wl0; D = wl0p; KT = 8; Kreal = 256; Nn = 128; id = idx - 303104; }
    else if (idx < 352256) { W = wl1; D = wl1p;         KT = 4; Kreal = 128; Nn = 128; id = idx - 335872; }
    else                   { W = wl1; D = wl1p + 16384; KT = 4; Kreal = 128; Nn = 128; id = idx - 352256; koff = 128; }
    int j = id & 7, lane = (id >> 3) & 63, tt = id >> 9;
    int kt = tt % KT, nt = tt / KT;
    int k = kt * 32 + ((lane >> 4) << 3) + j;
    int nn = nt * 16 + (lane & 15);
    D[id] = (k < Kreal) ? f2bf(W[(k + koff) * Nn + nn]) : (ushort)0;
}

// ---------------------------------------------------------------------------
// Node up/down projections, 16 nodes/block. u1 stored PLANAR.
// u1's 3 planes fused into one pass (Wu1 read once, not 3x).
// ---------------------------------------------------------------------------
__global__ __launch_bounds__(256) void node_uud_kernel(
    const float* __restrict__ nf,
    const float* __restrict__ Wu0, const float* __restrict__ Wu1,
    const float* __restrict__ Wd,
    ushort* __restrict__ u0, ushort* __restrict__ u1,
    ushort* __restrict__ down)
{
    __shared__ float x[NB * 512];
    int t = threadIdx.x;
    int n0 = blockIdx.x * NB;
    {
        const float4* src = (const float4*)(nf + (size_t)n0 * 512);
        float4* dst = (float4*)x;
        for (int i = t; i < NB * 128; i += 256) dst[i] = src[i];
    }
    __syncthreads();
    int v = t & 127, g = t >> 7;
    {
        float acc[8] = {0.f,0.f,0.f,0.f,0.f,0.f,0.f,0.f};
        for (int u = 0; u < 128; ++u) {
            float wv = Wu0[u * 128 + v];
#pragma unroll
            for (int j = 0; j < 8; ++j) acc[j] += x[(g * 8 + j) * 512 + u] * wv;
        }
#pragma unroll
        for (int j = 0; j < 8; ++j)
            u0[(size_t)(n0 + g * 8 + j) * 128 + v] = f2bf(acc[j] * INV_C);
    }
    {
        float acc[3][8] = {};
        for (int u = 0; u < 128; ++u) {
            float wv = Wu1[u * 128 + v];
#pragma unroll
            for (int j = 0; j < 8; ++j) {
                int b = (g * 8 + j) * 512 + 128 + u * 3;
                acc[0][j] += x[b + 0] * wv;
                acc[1][j] += x[b + 1] * wv;
                acc[2][j] += x[b + 2] * wv;
            }
        }
#pragma unroll
        for (int i = 0; i < 3; ++i)
#pragma unroll
            for (int j = 0; j < 8; ++j)
                u1[(size_t)(n0 + g * 8 + j) * 384 + i * 128 + v] = f2bf(acc[i][j] * INV_C);
    }
    {
        int vd = t & 63, gd = t >> 6;
        float acc[4] = {0.f,0.f,0.f,0.f};
        for (int u = 0; u < 128; ++u) {
            float wv = Wd[u * 64 + vd];
#pragma unroll
            for (int j = 0; j < 4; ++j) acc[j] += x[(gd * 4 + j) * 512 + u] * wv;
        }
#pragma unroll
        for (int j = 0; j < 4; ++j)
            down[(size_t)(n0 + gd * 4 + j) * 64 + vd] = f2bf(acc[j] * INV_C);
    }
}

// ---------------------------------------------------------------------------
// Skip connection, 16 nodes/block (runs LAST). Single-pass Ws1 (read once),
// results staged into x (dead after the pass) -> coalesced float4 writes.
// LDS back to 32 KB (R10's extra 24 KB buffer cost occupancy).
// ---------------------------------------------------------------------------
__global__ __launch_bounds__(256) void node_sc_kernel(
    const float* __restrict__ nf,
    const float* __restrict__ Ws0, const float* __restrict__ Ws1,
    float* __restrict__ out_sc)
{
    __shared__ float x[NB * 512];
    int t = threadIdx.x;
    int n0 = blockIdx.x * NB;
    {
        const float4* src = (const float4*)(nf + (size_t)n0 * 512);
        float4* dst = (float4*)x;
        for (int i = t; i < NB * 128; i += 256) dst[i] = src[i];
    }
    __syncthreads();
    int v = t & 127, g = t >> 7;
    {
        float acc[8] = {0.f,0.f,0.f,0.f,0.f,0.f,0.f,0.f};
        for (int u = 0; u < 128; ++u) {
            float wv = Ws0[u * 128 + v];
#pragma unroll
            for (int j = 0; j < 8; ++j) acc[j] += x[(g * 8 + j) * 512 + u] * wv;
        }
#pragma unroll
        for (int j = 0; j < 8; ++j)
            out_sc[(size_t)(n0 + g * 8 + j) * 512 + v] = fin(acc[j] * INV_C);
    }
    float acc[3][8] = {};
    for (int u = 0; u < 128; ++u) {
        float wv = Ws1[u * 128 + v];
#pragma unroll
        for (int j = 0; j < 8; ++j) {
            int b = (g * 8 + j) * 512 + 128 + u * 3;
            acc[0][j] += x[b + 0] * wv;
            acc[1][j] += x[b + 1] * wv;
            acc[2][j] += x[b + 2] * wv;
        }
    }
    __syncthreads();   // all reads of x done -> reuse x as [NB][384] staging
#pragma unroll
    for (int i = 0; i < 3; ++i)
#pragma unroll
        for (int j = 0; j < 8; ++j)
            x[(g * 8 + j) * 384 + v * 3 + i] = fin(acc[i][j] * INV_C);
    __syncthreads();
    for (int i = t; i < NB * 96; i += 256) {
        int nd = i / 96, k = i - nd * 96;
        *(float4*)&out_sc[(size_t)(n0 + nd) * 512 + 128 + k * 4] =
            *(const float4*)&x[nd * 384 + k * 4];
    }
}

// ---------------------------------------------------------------------------
// CSR build (receiver-sorted edge list).
// ---------------------------------------------------------------------------
__global__ __launch_bounds__(256) void hist_kernel(const int* __restrict__ eidx, int* __restrict__ counts)
{
    int e = blockIdx.x * 256 + threadIdx.x;
    int r = eidx[N_EDGES + e];
    if (r < 0) r = 0; if (r >= N_NODES) r = N_NODES - 1;
    atomicAdd(&counts[r], 1);
}

// Wave-shuffle scan: 4 barriers/chunk (was 20) -> ~40 total (was 200).
__global__ __launch_bounds__(1024) void scan_kernel(const int* __restrict__ counts, int* __restrict__ offs)
{
    __shared__ int wsum[16];
    __shared__ int base_s;
    int t = threadIdx.x, lane = t & 63, wid = t >> 6;
    if (t == 0) { base_s = 0; offs[0] = 0; }
    __syncthreads();
    for (int chunk = 0; chunk < (N_NODES + 1023) / 1024; ++chunk) {
        int i = chunk * 1024 + t;
        int v = (i < N_NODES) ? counts[i] : 0;
#pragma unroll
        for (int off = 1; off < 64; off <<= 1) {
            int u = __shfl_up(v, off, 64);
            if (lane >= off) v += u;
        }
        if (lane == 63) wsum[wid] = v;
        __syncthreads();
        if (wid == 0) {
            int s = (lane < 16) ? wsum[lane] : 0;
#pragma unroll
            for (int off = 1; off < 16; off <<= 1) {
                int u = __shfl_up(s, off, 64);
                if (lane >= off) s += u;
            }
            if (lane < 16) wsum[lane] = s;
        }
        __syncthreads();
        int prefix = (wid > 0) ? wsum[wid - 1] : 0;
        int incl = v + prefix;
        int base = base_s;
        __syncthreads();
        if (i < N_NODES) offs[i + 1] = base + incl;
        if (t == 1023) base_s = base + incl;
        __syncthreads();
    }
}

__global__ __launch_bounds__(256) void fill_kernel(
    const int* __restrict__ eidx, const int* __restrict__ offs,
    int* __restrict__ cnt2, int* __restrict__ esort)
{
    int e = blockIdx.x * 256 + threadIdx.x;
    int r = eidx[N_EDGES + e];
    if (r < 0) r = 0; if (r >= N_NODES) r = N_NODES - 1;
    int k = atomicAdd(&cnt2[r], 1);
    int pos = offs[r] + k;
    if (pos < 0) pos = 0; if (pos >= N_EDGES) pos = N_EDGES - 1;
    esort[pos] = e;
}

// ---------------------------------------------------------------------------
// Dual-m-tile hidden-layer GEMM: 32 edges (two 16-row m-tiles) x 256 out.
// ---------------------------------------------------------------------------
#define H_STRIDE 264

template <int KT, bool SILU>
__device__ __forceinline__ void gemm_layer(
    const ushort* __restrict__ wpack, const ushort* srcLDS, int srcStride,
    ushort* dstLDS, float scale)
{
    int t = threadIdx.x;
    int w = t >> 6, l = t & 63;
    int lrow = l & 15, q = l >> 4;

    for (int p = 0; p < 2; ++p) {
        int nt0 = w * 4 + 2 * p, nt1 = nt0 + 1;
        v4f a00 = {0.f,0.f,0.f,0.f}, a01 = {0.f,0.f,0.f,0.f};
        v4f a10 = {0.f,0.f,0.f,0.f}, a11 = {0.f,0.f,0.f,0.f};
#pragma unroll
        for (int kt = 0; kt < KT; ++kt) {
            v8s b0 = *(const v8s*)&wpack[(size_t)(nt0 * KT + kt) * 512 + l * 8];
            v8s b1 = *(const v8s*)&wpack[(size_t)(nt1 * KT + kt) * 512 + l * 8];
            v8s x0 = *(const v8s*)&srcLDS[lrow * srcStride + kt * 32 + q * 8];
            v8s x1 = *(const v8s*)&srcLDS[(16 + lrow) * srcStride + kt * 32 + q * 8];
            a00 = MFMA(x0, b0, a00, 0, 0, 0);
            a01 = MFMA(x0, b1, a01, 0, 0, 0);
            a10 = MFMA(x1, b0, a10, 0, 0, 0);
            a11 = MFMA(x1, b1, a11, 0, 0, 0);
        }
#pragma unroll
        for (int r = 0; r < 4; ++r) {
            float x00 = a00[r] * scale, x01 = a01[r] * scale;
            float x10 = a10[r] * scale, x11 = a11[r] * scale;
            if (SILU) {
                x00 = silu(x00); x01 = silu(x01);
                x10 = silu(x10); x11 = silu(x11);
            }
            int row0 = q * 4 + r, row1 = row0 + 16;
            unsigned p0 = cvt_pk_bf16(x00, x01);
            dstLDS[row0 * H_STRIDE + nt0 * 16 + lrow] = (ushort)p0;
            dstLDS[row0 * H_STRIDE + nt1 * 16 + lrow] = (ushort)(p0 >> 16);
            unsigned p1 = cvt_pk_bf16(x10, x11);
            dstLDS[row1 * H_STRIDE + nt0 * 16 + lrow] = (ushort)p1;
            dstLDS[row1 * H_STRIDE + nt1 * 16 + lrow] = (ushort)(p1 >> 16);
        }
    }
    __syncthreads();
}

// Segment-reduce the 32x128 fp32 tile in s_red over rows with equal s_rcv
// (receiver-sorted -> contiguous segments, ~2-3 per block) and atomicAdd
// one fp32 partial per (segment,col). Replaces the 164 MB tpw round-trip.
__device__ __forceinline__ void reduce_plane(
    const float* s_red, const int* s_rcv, float* __restrict__ out_msg, int cofs)
{
    int t = threadIdx.x;
    int c = t & 127, h = t >> 7;           // h: rows [h*16, h*16+16)
    float sum = 0.f;
    int cur = s_rcv[h * 16];
#pragma unroll
    for (int row = h * 16; row < h * 16 + 16; ++row) {
        int rcv = s_rcv[row];
        if (rcv != cur) {
            atomicAdd(&out_msg[(size_t)cur * 512 + c * 4 + cofs], sum);
            sum = 0.f; cur = rcv;
        }
        sum += s_red[row * 128 + c];
    }
    atomicAdd(&out_msg[(size_t)cur * 512 + c * 4 + cofs], sum);
}

// Output GEMM [32x256]@[256x128], dual-m -> fp32 tile in s_red -> reduce.
__device__ __forceinline__ void gemm_out(
    const ushort* __restrict__ wpack, const ushort* srcLDS,
    const int* s_rcv, float* __restrict__ out_msg, float* s_red, int cofs)
{
    int t = threadIdx.x;
    int w = t >> 6, l = t & 63;
    int lrow = l & 15, q = l >> 4;
    int nt0 = w * 2, nt1 = nt0 + 1;
    v4f a00 = {0.f,0.f,0.f,0.f}, a01 = {0.f,0.f,0.f,0.f};
    v4f a10 = {0.f,0.f,0.f,0.f}, a11 = {0.f,0.f,0.f,0.f};
#pragma unroll
    for (int kt = 0; kt < 8; ++kt) {
        v8s b0 = *(const v8s*)&wpack[(size_t)(nt0 * 8 + kt) * 512 + l * 8];
        v8s b1 = *(const v8s*)&wpack[(size_t)(nt1 * 8 + kt) * 512 + l * 8];
        v8s x0 = *(const v8s*)&srcLDS[lrow * H_STRIDE + kt * 32 + q * 8];
        v8s x1 = *(const v8s*)&srcLDS[(16 + lrow) * H_STRIDE + kt * 32 + q * 8];
        a00 = MFMA(x0, b0, a00, 0, 0, 0);
        a01 = MFMA(x0, b1, a01, 0, 0, 0);
        a10 = MFMA(x1, b0, a10, 0, 0, 0);
        a11 = MFMA(x1, b1, a11, 0, 0, 0);
    }
    int col0 = nt0 * 16 + lrow, col1 = col0 + 16;
#pragma unroll
    for (int r = 0; r < 4; ++r) {
        int row0 = q * 4 + r, row1 = row0 + 16;
        s_red[row0 * 128 + col0] = a00[r] * OUT_SCALE;
        s_red[row0 * 128 + col1] = a01[r] * OUT_SCALE;
        s_red[row1 * 128 + col0] = a10[r] * OUT_SCALE;
        s_red[row1 * 128 + col1] = a11[r] * OUT_SCALE;
    }
    __syncthreads();
    reduce_plane(s_red, s_rcv, out_msg, cofs);
}

// ---------------------------------------------------------------------------
// Edge-parallel fused kernel: EB=32, 4 waves, dual m-tile, RECEIVER-SORTED.
// Output: in-LDS segment reduction + fp32 atomic partials (no tpw, no gather).
// s_red reuses s_hA (dead after layer 4; 32*128*4 B = 16384 <= 16896 B).
// __launch_bounds__(256,3): VGPR budget ~85, no spill (gfx950 law 256/minw).
// ---------------------------------------------------------------------------
__global__ __launch_bounds__(256, 3) void edge_msg_kernel(
    const int* __restrict__ eidx, const int* __restrict__ esort,
    const float* __restrict__ ef, const float* __restrict__ ea,
    const ushort* __restrict__ down,
    const ushort* __restrict__ u0, const ushort* __restrict__ u1,
    const ushort* __restrict__ w1p, const ushort* __restrict__ w2p,
    const ushort* __restrict__ w3p, const ushort* __restrict__ w4p,
    const ushort* __restrict__ wl0p, const ushort* __restrict__ wl1p,
    float* __restrict__ out_msg)
{
    __shared__ __align__(16) ushort s_hA[EB * H_STRIDE];
    __shared__ __align__(16) ushort s_hB[EB * H_STRIDE];
    __shared__ __align__(16) ushort s_q[EB * H_STRIDE];   // q1 [0,128), q2 [128,256)
    __shared__ int s_snd[EB];
    __shared__ int s_rcv[EB];
    __shared__ int s_eid[EB];
    __shared__ float s_y[EB][4];

    float* s_red = (float*)s_hA;   // 32x128 fp32 reduction tile (aliases s_hA)

    int t = threadIdx.x;
    int e0 = blockIdx.x * EB;

    if (t < EB) {
        int e = esort[e0 + t];
        if (e < 0) e = 0; if (e >= N_EDGES) e = N_EDGES - 1;
        s_eid[t] = e;
        int s = eidx[e];
        int r = eidx[N_EDGES + e];
        if (s < 0) s = 0; if (s >= N_NODES) s = N_NODES - 1;
        if (r < 0) r = 0; if (r >= N_NODES) r = N_NODES - 1;
        s_snd[t] = s; s_rcv[t] = r;
        s_y[t][0] = fin(ea[(size_t)e * 4 + 0]);
        s_y[t][1] = fin(ea[(size_t)e * 4 + 1]);
        s_y[t][2] = fin(ea[(size_t)e * 4 + 2]);
        s_y[t][3] = fin(ea[(size_t)e * 4 + 3]);
    }
    __syncthreads();
    // stage aug into s_hB stride 168 — 8 threads/edge, 21 cols each (8*21=168)
    {
        int e = t >> 3, c0 = (t & 7) * 21;
        int snd = s_snd[e], rcv = s_rcv[e], eid = s_eid[e];
#pragma unroll
        for (int j = 0; j < 21; ++j) {
            int cc = c0 + j;
            ushort vv;
            if (cc < 8)        vv = f2bf(ef[(size_t)eid * 8 + cc]);
            else if (cc < 72)  vv = down[(size_t)snd * 64 + (cc - 8)];
            else if (cc < 136) vv = down[(size_t)rcv * 64 + (cc - 72)];
            else               vv = 0;
            s_hB[e * 168 + cc] = vv;
        }
    }
    __syncthreads();
    gemm_layer<5, true>(w1p, s_hB, 168, s_hA, S_MLP1);       // aug -> hA
    gemm_layer<8, true>(w2p, s_hA, H_STRIDE, s_hB, S_MLP);   // hA  -> hB
    gemm_layer<8, true>(w3p, s_hB, H_STRIDE, s_hA, S_MLP);   // hB  -> hA

    // ---- layer 4 quarters (dual-m, in-loop A reads from hA) ----
    int w = t >> 6, l = t & 63;
    int lrow = l & 15, q = l >> 4;
    int colg0 = w * 32 + lrow, colg1 = colg0 + 16;

    for (int qd = 0; qd < 4; ++qd) {
        int nt0 = qd * 8 + w * 2, nt1 = nt0 + 1;
        v4f a00 = {0.f,0.f,0.f,0.f}, a01 = {0.f,0.f,0.f,0.f};
        v4f a10 = {0.f,0.f,0.f,0.f}, a11 = {0.f,0.f,0.f,0.f};
#pragma unroll
        for (int kt = 0; kt < 8; ++kt) {
            v8s b0 = *(const v8s*)&w4p[(size_t)(nt0 * 8 + kt) * 512 + l * 8];
            v8s b1 = *(const v8s*)&w4p[(size_t)(nt1 * 8 + kt) * 512 + l * 8];
            v8s x0 = *(const v8s*)&s_hA[lrow * H_STRIDE + kt * 32 + q * 8];
            v8s x1 = *(const v8s*)&s_hA[(16 + lrow) * H_STRIDE + kt * 32 + q * 8];
            a00 = MFMA(x0, b0, a00, 0, 0, 0);
            a01 = MFMA(x0, b1, a01, 0, 0, 0);
            a10 = MFMA(x1, b0, a10, 0, 0, 0);
            a11 = MFMA(x1, b1, a11, 0, 0, 0);
        }
#pragma unroll
        for (int r = 0; r < 4; ++r) {
#pragma unroll
            for (int m = 0; m < 2; ++m) {
                int row = m * 16 + q * 4 + r;
                float v0 = (m == 0 ? a00[r] : a10[r]) * S_MLP;
                float v1 = (m == 0 ? a01[r] : a11[r]) * S_MLP;
                int snd = s_snd[row];
                if (qd == 0) {
                    float y0 = s_y[row][0];
                    float ua = bf2f(u0[(size_t)snd * 128 + colg0]);
                    float ub = bf2f(u0[(size_t)snd * 128 + colg1]);
                    unsigned pk = cvt_pk_bf16(v0 * ua * y0, v1 * ub * y0);
                    s_hB[row * H_STRIDE + colg0] = (ushort)pk;
                    s_hB[row * H_STRIDE + colg1] = (ushort)(pk >> 16);
                } else if (qd == 1) {
                    float ua = bf2f(u0[(size_t)snd * 128 + colg0]);
                    float ub = bf2f(u0[(size_t)snd * 128 + colg1]);
                    unsigned pk = cvt_pk_bf16(v0 * ua, v1 * ub);
                    s_q[row * H_STRIDE + colg0] = (ushort)pk;
                    s_q[row * H_STRIDE + colg1] = (ushort)(pk >> 16);
                } else if (qd == 2) {
                    unsigned pk = cvt_pk_bf16(v0, v1);
                    s_q[row * H_STRIDE + 128 + colg0] = (ushort)pk;
                    s_q[row * H_STRIDE + 128 + colg1] = (ushort)(pk >> 16);
                } else {
                    size_t ub_ = (size_t)snd * 384;
                    float d0 = bf2f(u1[ub_ + colg0])       * s_y[row][1]
                             + bf2f(u1[ub_ + 128 + colg0]) * s_y[row][2]
                             + bf2f(u1[ub_ + 256 + colg0]) * s_y[row][3];
                    float d1 = bf2f(u1[ub_ + colg1])       * s_y[row][1]
                             + bf2f(u1[ub_ + 128 + colg1]) * s_y[row][2]
                             + bf2f(u1[ub_ + 256 + colg1]) * s_y[row][3];
                    unsigned pk = cvt_pk_bf16(v0 * d0 * INV_SQRT3, v1 * d1 * INV_SQRT3);
                    s_hB[row * H_STRIDE + 128 + colg0] = (ushort)pk;
                    s_hB[row * H_STRIDE + 128 + colg1] = (ushort)(pk >> 16);
                }
            }
        }
    }
    __syncthreads();   // layer-4 done; s_hA becomes s_red from here on

    gemm_out(wl0p, s_hB, s_rcv, out_msg, s_red, 0);
    __syncthreads();   // s_red reads done before next plane overwrites

    // ---- wl1 with Z-factorization (dual-m) ----
    const ushort* wl1t = wl1p;            // rows [0,128)  of W_lin1, KT=4
    const ushort* wl1b = wl1p + 16384;    // rows [128,256) of W_lin1, KT=4
    int ntz0 = w * 2, ntz1 = ntz0 + 1;

    // Z = q1 @ wl1_top, held in regs across the i-loop
    v4f z00 = {0.f,0.f,0.f,0.f}, z01 = {0.f,0.f,0.f,0.f};
    v4f z10 = {0.f,0.f,0.f,0.f}, z11 = {0.f,0.f,0.f,0.f};
#pragma unroll
    for (int kt = 0; kt < 4; ++kt) {
        v8s b0 = *(const v8s*)&wl1t[(size_t)(ntz0 * 4 + kt) * 512 + l * 8];
        v8s b1 = *(const v8s*)&wl1t[(size_t)(ntz1 * 4 + kt) * 512 + l * 8];
        v8s x0 = *(const v8s*)&s_q[lrow * H_STRIDE + kt * 32 + q * 8];
        v8s x1 = *(const v8s*)&s_q[(16 + lrow) * H_STRIDE + kt * 32 + q * 8];
        z00 = MFMA(x0, b0, z00, 0, 0, 0);
        z01 = MFMA(x0, b1, z01, 0, 0, 0);
        z10 = MFMA(x1, b0, z10, 0, 0, 0);
        z11 = MFMA(x1, b1, z11, 0, 0, 0);
    }

    int colz0 = ntz0 * 16 + lrow, colz1 = colz0 + 16;
    for (int i = 0; i < 3; ++i) {
        // rebuild q2*u1_i*y0 into s_hB cols [0,128), 2-wide packed
#pragma unroll
        for (int it = 0; it < 8; ++it) {
            int idx = t + it * 256;
            int e = idx >> 6, kp = (idx & 63) << 1;
            unsigned uq = *(const unsigned*)&s_q[e * H_STRIDE + 128 + kp];
            unsigned uu = *(const unsigned*)&u1[(size_t)s_snd[e] * 384 + i * 128 + kp];
            float y0 = s_y[e][0];
            float lo = bf2f((ushort)uq) * bf2f((ushort)uu) * y0;
            float hi = bf2f((ushort)(uq >> 16)) * bf2f((ushort)(uu >> 16)) * y0;
            *(unsigned*)&s_hB[e * H_STRIDE + kp] = cvt_pk_bf16(lo, hi);
        }
        __syncthreads();
        // P_i = rebuilt @ wl1_bot; out = y_{1+i}*Z + P_i -> s_red -> reduce
        v4f p00 = {0.f,0.f,0.f,0.f}, p01 = {0.f,0.f,0.f,0.f};
        v4f p10 = {0.f,0.f,0.f,0.f}, p11 = {0.f,0.f,0.f,0.f};
#pragma unroll
        for (int kt = 0; kt < 4; ++kt) {
            v8s b0 = *(const v8s*)&wl1b[(size_t)(ntz0 * 4 + kt) * 512 + l * 8];
            v8s b1 = *(const v8s*)&wl1b[(size_t)(ntz1 * 4 + kt) * 512 + l * 8];
            v8s x0 = *(const v8s*)&s_hB[lrow * H_STRIDE + kt * 32 + q * 8];
            v8s x1 = *(const v8s*)&s_hB[(16 + lrow) * H_STRIDE + kt * 32 + q * 8];
            p00 = MFMA(x0, b0, p00, 0, 0, 0);
            p01 = MFMA(x0, b1, p01, 0, 0, 0);
            p10 = MFMA(x1, b0, p10, 0, 0, 0);
            p11 = MFMA(x1, b1, p11, 0, 0, 0);
        }
#pragma unroll
        for (int r = 0; r < 4; ++r) {
            int row0 = q * 4 + r, row1 = row0 + 16;
            float yi0 = s_y[row0][1 + i], yi1 = s_y[row1][1 + i];
            s_red[row0 * 128 + colz0] = (yi0 * z00[r] + p00[r]) * OUT_SCALE;
            s_red[row0 * 128 + colz1] = (yi0 * z01[r] + p01[r]) * OUT_SCALE;
            s_red[row1 * 128 + colz0] = (yi1 * z10[r] + p10[r]) * OUT_SCALE;
            s_red[row1 * 128 + colz1] = (yi1 * z11[r] + p11[r]) * OUT_SCALE;
        }
        __syncthreads();
        reduce_plane(s_red, s_rcv, out_msg, 1 + i);
        __syncthreads();   // s_red / s_hB safe for next iteration
    }
}

// ---------------------------------------------------------------------------
extern "C" void kernel_launch(void* const* d_in, const int* in_sizes, int n_in,
                              void* d_out, int out_size, void* d_ws, size_t ws_size,
                              hipStream_t stream)
{
    const float* node_feats = (const float*)d_in[1];
    const float* edge_attrs = (const float*)d_in[2];
    const float* edge_feats = (const float*)d_in[3];
    const int*   edge_index = (const int*)d_in[4];
    const float* W_up0  = (const float*)d_in[5];
    const float* W_up1  = (const float*)d_in[6];
    const float* W_down = (const float*)d_in[7];
    const float* mlp_w1 = (const float*)d_in[8];
    const float* mlp_w2 = (const float*)d_in[9];
    const float* mlp_w3 = (const float*)d_in[10];
    const float* mlp_w4 = (const float*)d_in[11];
    const float* W_lin0 = (const float*)d_in[12];
    const float* W_lin1 = (const float*)d_in[13];
    const float* W_skip0 = (const float*)d_in[14];
    const float* W_skip1 = (const float*)d_in[15];

    // d_out fp32: [message: 20,480,000 B][sc: 20,480,000 B]
    char* S = (char*)d_out + 20480000;   // sc half = scratch until node_sc

    ushort* u0    = (ushort*)(S + 0);           //  2,560,000 B
    ushort* down  = (ushort*)(S + 2560000);     //  1,280,000 B
    ushort* u1    = (ushort*)(S + 3840000);     //  7,680,000 B (planar [n][i][128])
    ushort* w1p   = (ushort*)(S + 11520000);    //     81,920 B
    ushort* w2p   = (ushort*)(S + 11601920);    //    131,072 B
    ushort* w3p   = (ushort*)(S + 11732992);    //    131,072 B
    ushort* w4p   = (ushort*)(S + 11864064);    //    262,144 B
    ushort* wl0p  = (ushort*)(S + 12126208);    //     65,536 B
    ushort* wl1p  = (ushort*)(S + 12191744);    //     65,536 B (top 32K + bottom 32K)
    int*    offs  = (int*)(S + 12257280);       //     40,032 B
    int*    esort = (int*)(S + 12297312);       //    640,000 B
    int*    counts= (int*)(S + 12937312);       //     40,000 B
    int*    cnt2  = (int*)(S + 12977312);       //     40,000 B -> 13,017,312

    float* out_msg = (float*)d_out;
    float* out_sc  = (float*)d_out + (size_t)N_NODES * 512;

    pack_kernel<<<1440, 256, 0, stream>>>(mlp_w1, mlp_w2, mlp_w3, mlp_w4, W_lin0, W_lin1,
                                          w1p, w2p, w3p, w4p, wl0p, wl1p);
    node_uud_kernel<<<N_NODES / NB, 256, 0, stream>>>(node_feats, W_up0, W_up1, W_down, u0, u1, down);

    hipMemsetAsync(counts, 0, 80000, stream);
    hipMemsetAsync(out_msg, 0, 20480000, stream);
    hist_kernel<<<N_EDGES / 256, 256, 0, stream>>>(edge_index, counts);
    scan_kernel<<<1, 1024, 0, stream>>>(counts, offs);
    fill_kernel<<<N_EDGES / 256, 256, 0, stream>>>(edge_index, offs, cnt2, esort);

    edge_msg_kernel<<<N_EDGES / EB, 256, 0, stream>>>(edge_index, esort,
        edge_feats, edge_attrs,
        down, u0, u1, w1p, w2p, w3p, w4p, wl0p, wl1p, out_msg);

    node_sc_kernel<<<N_NODES / NB, 256, 0, stream>>>(node_feats, W_skip0, W_skip1, out_sc);
}

// Round 12
// 538.773 us; speedup vs baseline: 1.1159x; 1.0248x over previous
//
#include <hip/hip_runtime.h>
#include <hip/hip_bf16.h>

#define N_NODES 10000
#define N_EDGES 160000
#define EB 32   /* edges per block (dual m-tile) */
#define NB 16   /* nodes per block in node kernels */
#define XT_S 20 /* transposed-x LDS stride: %4==0 for aligned float4 reads */
#define RED_S 130 /* s_red stride: breaks 4-way bank conflict of 128 */

typedef short v8s __attribute__((ext_vector_type(8)));
typedef float v4f __attribute__((ext_vector_type(4)));

__device__ __forceinline__ float bf2f(ushort u) {
    union { unsigned i; float f; } x; x.i = ((unsigned)u) << 16; return x.f;
}
__device__ __forceinline__ float fin(float x) {
    return (x == x) ? fminf(fmaxf(x, -1e30f), 1e30f) : 0.f;
}
__device__ __forceinline__ ushort f2bf(float f) {
    union { unsigned i; float f; } x; x.f = fin(f);
    unsigned i = x.i;
    unsigned r = (i + 0x7fffu + ((i >> 16) & 1u)) >> 16;
    return (ushort)r;
}
// HW packed f32x2 -> bf16x2 (RNE), one VALU op instead of ~10.
__device__ __forceinline__ unsigned cvt_pk_bf16(float lo, float hi) {
    unsigned r;
    asm("v_cvt_pk_bf16_f32 %0, %1, %2" : "=v"(r) : "v"(lo), "v"(hi));
    return r;
}
// Raw v_rcp_f32 (~1 ulp) — bf16 output rounding absorbs the error.
__device__ __forceinline__ float fast_rcp(float x) {
    float r;
    asm("v_rcp_f32 %0, %1" : "=v"(r) : "v"(x));
    return r;
}
__device__ __forceinline__ float silu(float x) {
    return x * fast_rcp(1.f + __expf(-x));
}

#define INV_C 0.08838834764831845f      /* 1/sqrt(128) */
#define S_MLP1 0.08574929257125442f     /* 1/sqrt(136) */
#define S_MLP 0.0625f                   /* 1/16 */
#define INV_SQRT3 0.5773502691896258f
#define OUT_SCALE 0.00390625f           /* (1/sqrt(256))/16 */

#define MFMA __builtin_amdgcn_mfma_f32_16x16x32_bf16

// ---------------------------------------------------------------------------
// Weight pre-pack: fp32 -> bf16 MFMA B-fragment order.
// wl1 packed as TWO K=128 halves (top / bottom) for the Z-factorization.
// ---------------------------------------------------------------------------
__global__ __launch_bounds__(256) void pack_kernel(
    const float* __restrict__ w1, const float* __restrict__ w2,
    const float* __restrict__ w3, const float* __restrict__ w4,
    const float* __restrict__ wl0, const float* __restrict__ wl1,
    ushort* __restrict__ w1p, ushort* __restrict__ w2p,
    ushort* __restrict__ w3p, ushort* __restrict__ w4p,
    ushort* __restrict__ wl0p, ushort* __restrict__ wl1p)
{
    int idx = blockIdx.x * 256 + threadIdx.x;
    const float* W; ushort* D; int KT, Kreal, Nn, id, koff = 0;
    if (idx < 40960)       { W = w1;  D = w1p;  KT = 5; Kreal = 136; Nn = 256; id = idx; }
    else if (idx < 106496) { W = w2;  D = w2p;  KT = 8; Kreal = 256; Nn = 256; id = idx - 40960; }
    else if (idx < 172032) { W = w3;  D = w3p;  KT = 8; Kreal = 256; Nn = 256; id = idx - 106496; }
    else if (idx < 303104) { W = w4;  D = w4p;  KT = 8; Kreal = 256; Nn = 512; id = idx - 172032; }
    else if (idx < 335872) { W = wl0; D = wl0p; KT = 8; Kreal = 256; Nn = 128; id = idx - 303104; }
    else if (idx < 352256) { W = wl1; D = wl1p;         KT = 4; Kreal = 128; Nn = 128; id = idx - 335872; }
    else                   { W = wl1; D = wl1p + 16384; KT = 4; Kreal = 128; Nn = 128; id = idx - 352256; koff = 128; }
    int j = id & 7, lane = (id >> 3) & 63, tt = id >> 9;
    int kt = tt % KT, nt = tt / KT;
    int k = kt * 32 + ((lane >> 4) << 3) + j;
    int nn = nt * 16 + (lane & 15);
    D[id] = (k < Kreal) ? f2bf(W[(k + koff) * Nn + nn]) : (ushort)0;
}

// ---------------------------------------------------------------------------
// Node up/down projections, 16 nodes/block. u1 PLANAR. TRANSPOSED x staging:
// xt[u][node] -> the 8 per-node reads per W element become 2 broadcast
// ds_read_b128 (was 8 scalar ds_read_b32). Numerics bit-identical (same fp32
// FMA order); only the load instruction shape changes.
// ---------------------------------------------------------------------------
__global__ __launch_bounds__(256) void node_uud_kernel(
    const float* __restrict__ nf,
    const float* __restrict__ Wu0, const float* __restrict__ Wu1,
    const float* __restrict__ Wd,
    ushort* __restrict__ u0, ushort* __restrict__ u1,
    ushort* __restrict__ down)
{
    __shared__ float xt0[128 * XT_S];   // x0 transposed [u][node]
    __shared__ float xt1[384 * XT_S];   // x1 transposed [u*3+i][node]
    int t = threadIdx.x;
    int n0 = blockIdx.x * NB;
    for (int i = t; i < NB * 128; i += 256) {
        int nd = i >> 7, m = i & 127;                 // coalesced global read
        xt0[m * XT_S + nd] = nf[(size_t)(n0 + nd) * 512 + m];
    }
    for (int i = t; i < NB * 384; i += 256) {
        int nd = i / 384, m = i - nd * 384;
        xt1[m * XT_S + nd] = nf[(size_t)(n0 + nd) * 512 + 128 + m];
    }
    __syncthreads();
    int v = t & 127, g = t >> 7;
    {
        float acc[8] = {0.f,0.f,0.f,0.f,0.f,0.f,0.f,0.f};
        for (int u = 0; u < 128; ++u) {
            float wv = Wu0[u * 128 + v];
            const float4* xr = (const float4*)&xt0[u * XT_S + g * 8];
            float4 xa = xr[0], xb = xr[1];
            acc[0] += xa.x * wv; acc[1] += xa.y * wv;
            acc[2] += xa.z * wv; acc[3] += xa.w * wv;
            acc[4] += xb.x * wv; acc[5] += xb.y * wv;
            acc[6] += xb.z * wv; acc[7] += xb.w * wv;
        }
#pragma unroll
        for (int j = 0; j < 8; ++j)
            u0[(size_t)(n0 + g * 8 + j) * 128 + v] = f2bf(acc[j] * INV_C);
    }
    {
        float acc[3][8] = {};
        for (int u = 0; u < 128; ++u) {
            float wv = Wu1[u * 128 + v];
#pragma unroll
            for (int i = 0; i < 3; ++i) {
                const float4* xr = (const float4*)&xt1[(u * 3 + i) * XT_S + g * 8];
                float4 xa = xr[0], xb = xr[1];
                acc[i][0] += xa.x * wv; acc[i][1] += xa.y * wv;
                acc[i][2] += xa.z * wv; acc[i][3] += xa.w * wv;
                acc[i][4] += xb.x * wv; acc[i][5] += xb.y * wv;
                acc[i][6] += xb.z * wv; acc[i][7] += xb.w * wv;
            }
        }
#pragma unroll
        for (int i = 0; i < 3; ++i)
#pragma unroll
            for (int j = 0; j < 8; ++j)
                u1[(size_t)(n0 + g * 8 + j) * 384 + i * 128 + v] = f2bf(acc[i][j] * INV_C);
    }
    {
        int vd = t & 63, gd = t >> 6;
        float acc[4] = {0.f,0.f,0.f,0.f};
        for (int u = 0; u < 128; ++u) {
            float wv = Wd[u * 64 + vd];
            const float4* xr = (const float4*)&xt0[u * XT_S + gd * 4];
            float4 xa = xr[0];
            acc[0] += xa.x * wv; acc[1] += xa.y * wv;
            acc[2] += xa.z * wv; acc[3] += xa.w * wv;
        }
#pragma unroll
        for (int j = 0; j < 4; ++j)
            down[(size_t)(n0 + gd * 4 + j) * 64 + vd] = f2bf(acc[j] * INV_C);
    }
}

// ---------------------------------------------------------------------------
// Skip connection, 16 nodes/block (runs LAST). Transposed staging like uud;
// sc1 results staged into xt1 (dead after compute) -> coalesced float4 out.
// ---------------------------------------------------------------------------
__global__ __launch_bounds__(256) void node_sc_kernel(
    const float* __restrict__ nf,
    const float* __restrict__ Ws0, const float* __restrict__ Ws1,
    float* __restrict__ out_sc)
{
    __shared__ float xt0[128 * XT_S];
    __shared__ float xt1[384 * XT_S];
    int t = threadIdx.x;
    int n0 = blockIdx.x * NB;
    for (int i = t; i < NB * 128; i += 256) {
        int nd = i >> 7, m = i & 127;
        xt0[m * XT_S + nd] = nf[(size_t)(n0 + nd) * 512 + m];
    }
    for (int i = t; i < NB * 384; i += 256) {
        int nd = i / 384, m = i - nd * 384;
        xt1[m * XT_S + nd] = nf[(size_t)(n0 + nd) * 512 + 128 + m];
    }
    __syncthreads();
    int v = t & 127, g = t >> 7;
    {
        float acc[8] = {0.f,0.f,0.f,0.f,0.f,0.f,0.f,0.f};
        for (int u = 0; u < 128; ++u) {
            float wv = Ws0[u * 128 + v];
            const float4* xr = (const float4*)&xt0[u * XT_S + g * 8];
            float4 xa = xr[0], xb = xr[1];
            acc[0] += xa.x * wv; acc[1] += xa.y * wv;
            acc[2] += xa.z * wv; acc[3] += xa.w * wv;
            acc[4] += xb.x * wv; acc[5] += xb.y * wv;
            acc[6] += xb.z * wv; acc[7] += xb.w * wv;
        }
#pragma unroll
        for (int j = 0; j < 8; ++j)
            out_sc[(size_t)(n0 + g * 8 + j) * 512 + v] = fin(acc[j] * INV_C);
    }
    float acc[3][8] = {};
    for (int u = 0; u < 128; ++u) {
        float wv = Ws1[u * 128 + v];
#pragma unroll
        for (int i = 0; i < 3; ++i) {
            const float4* xr = (const float4*)&xt1[(u * 3 + i) * XT_S + g * 8];
            float4 xa = xr[0], xb = xr[1];
            acc[i][0] += xa.x * wv; acc[i][1] += xa.y * wv;
            acc[i][2] += xa.z * wv; acc[i][3] += xa.w * wv;
            acc[i][4] += xb.x * wv; acc[i][5] += xb.y * wv;
            acc[i][6] += xb.z * wv; acc[i][7] += xb.w * wv;
        }
    }
    __syncthreads();   // xt1 reads done -> reuse as [NB][384] staging
#pragma unroll
    for (int i = 0; i < 3; ++i)
#pragma unroll
        for (int j = 0; j < 8; ++j)
            xt1[(g * 8 + j) * 384 + v * 3 + i] = fin(acc[i][j] * INV_C);
    __syncthreads();
    for (int i = t; i < NB * 96; i += 256) {
        int nd = i / 96, k = i - nd * 96;
        *(float4*)&out_sc[(size_t)(n0 + nd) * 512 + 128 + k * 4] =
            *(const float4*)&xt1[nd * 384 + k * 4];
    }
}

// ---------------------------------------------------------------------------
// CSR build (receiver-sorted edge list).
// ---------------------------------------------------------------------------
__global__ __launch_bounds__(256) void hist_kernel(const int* __restrict__ eidx, int* __restrict__ counts)
{
    int e = blockIdx.x * 256 + threadIdx.x;
    int r = eidx[N_EDGES + e];
    if (r < 0) r = 0; if (r >= N_NODES) r = N_NODES - 1;
    atomicAdd(&counts[r], 1);
}

// Wave-shuffle scan: 4 barriers/chunk.
__global__ __launch_bounds__(1024) void scan_kernel(const int* __restrict__ counts, int* __restrict__ offs)
{
    __shared__ int wsum[16];
    __shared__ int base_s;
    int t = threadIdx.x, lane = t & 63, wid = t >> 6;
    if (t == 0) { base_s = 0; offs[0] = 0; }
    __syncthreads();
    for (int chunk = 0; chunk < (N_NODES + 1023) / 1024; ++chunk) {
        int i = chunk * 1024 + t;
        int v = (i < N_NODES) ? counts[i] : 0;
#pragma unroll
        for (int off = 1; off < 64; off <<= 1) {
            int u = __shfl_up(v, off, 64);
            if (lane >= off) v += u;
        }
        if (lane == 63) wsum[wid] = v;
        __syncthreads();
        if (wid == 0) {
            int s = (lane < 16) ? wsum[lane] : 0;
#pragma unroll
            for (int off = 1; off < 16; off <<= 1) {
                int u = __shfl_up(s, off, 64);
                if (lane >= off) s += u;
            }
            if (lane < 16) wsum[lane] = s;
        }
        __syncthreads();
        int prefix = (wid > 0) ? wsum[wid - 1] : 0;
        int incl = v + prefix;
        int base = base_s;
        __syncthreads();
        if (i < N_NODES) offs[i + 1] = base + incl;
        if (t == 1023) base_s = base + incl;
        __syncthreads();
    }
}

__global__ __launch_bounds__(256) void fill_kernel(
    const int* __restrict__ eidx, const int* __restrict__ offs,
    int* __restrict__ cnt2, int* __restrict__ esort)
{
    int e = blockIdx.x * 256 + threadIdx.x;
    int r = eidx[N_EDGES + e];
    if (r < 0) r = 0; if (r >= N_NODES) r = N_NODES - 1;
    int k = atomicAdd(&cnt2[r], 1);
    int pos = offs[r] + k;
    if (pos < 0) pos = 0; if (pos >= N_EDGES) pos = N_EDGES - 1;
    esort[pos] = e;
}

// ---------------------------------------------------------------------------
// Dual-m-tile hidden-layer GEMM: 32 edges (two 16-row m-tiles) x 256 out.
// ---------------------------------------------------------------------------
#define H_STRIDE 264

template <int KT, bool SILU>
__device__ __forceinline__ void gemm_layer(
    const ushort* __restrict__ wpack, const ushort* srcLDS, int srcStride,
    ushort* dstLDS, float scale)
{
    int t = threadIdx.x;
    int w = t >> 6, l = t & 63;
    int lrow = l & 15, q = l >> 4;

    for (int p = 0; p < 2; ++p) {
        int nt0 = w * 4 + 2 * p, nt1 = nt0 + 1;
        v4f a00 = {0.f,0.f,0.f,0.f}, a01 = {0.f,0.f,0.f,0.f};
        v4f a10 = {0.f,0.f,0.f,0.f}, a11 = {0.f,0.f,0.f,0.f};
#pragma unroll
        for (int kt = 0; kt < KT; ++kt) {
            v8s b0 = *(const v8s*)&wpack[(size_t)(nt0 * KT + kt) * 512 + l * 8];
            v8s b1 = *(const v8s*)&wpack[(size_t)(nt1 * KT + kt) * 512 + l * 8];
            v8s x0 = *(const v8s*)&srcLDS[lrow * srcStride + kt * 32 + q * 8];
            v8s x1 = *(const v8s*)&srcLDS[(16 + lrow) * srcStride + kt * 32 + q * 8];
            a00 = MFMA(x0, b0, a00, 0, 0, 0);
            a01 = MFMA(x0, b1, a01, 0, 0, 0);
            a10 = MFMA(x1, b0, a10, 0, 0, 0);
            a11 = MFMA(x1, b1, a11, 0, 0, 0);
        }
#pragma unroll
        for (int r = 0; r < 4; ++r) {
            float x00 = a00[r] * scale, x01 = a01[r] * scale;
            float x10 = a10[r] * scale, x11 = a11[r] * scale;
            if (SILU) {
                x00 = silu(x00); x01 = silu(x01);
                x10 = silu(x10); x11 = silu(x11);
            }
            int row0 = q * 4 + r, row1 = row0 + 16;
            unsigned p0 = cvt_pk_bf16(x00, x01);
            dstLDS[row0 * H_STRIDE + nt0 * 16 + lrow] = (ushort)p0;
            dstLDS[row0 * H_STRIDE + nt1 * 16 + lrow] = (ushort)(p0 >> 16);
            unsigned p1 = cvt_pk_bf16(x10, x11);
            dstLDS[row1 * H_STRIDE + nt0 * 16 + lrow] = (ushort)p1;
            dstLDS[row1 * H_STRIDE + nt1 * 16 + lrow] = (ushort)(p1 >> 16);
        }
    }
    __syncthreads();
}

// Segment-reduce the 32x128 fp32 tile (stride RED_S) over rows with equal
// s_rcv and atomicAdd one fp32 partial per (segment,col).
__device__ __forceinline__ void reduce_plane(
    const float* s_red, const int* s_rcv, float* __restrict__ out_msg, int cofs)
{
    int t = threadIdx.x;
    int c = t & 127, h = t >> 7;           // h: rows [h*16, h*16+16)
    float sum = 0.f;
    int cur = s_rcv[h * 16];
#pragma unroll
    for (int row = h * 16; row < h * 16 + 16; ++row) {
        int rcv = s_rcv[row];
        if (rcv != cur) {
            atomicAdd(&out_msg[(size_t)cur * 512 + c * 4 + cofs], sum);
            sum = 0.f; cur = rcv;
        }
        sum += s_red[row * RED_S + c];
    }
    atomicAdd(&out_msg[(size_t)cur * 512 + c * 4 + cofs], sum);
}

// Output GEMM [32x256]@[256x128], dual-m -> fp32 tile in s_red -> reduce.
__device__ __forceinline__ void gemm_out(
    const ushort* __restrict__ wpack, const ushort* srcLDS,
    const int* s_rcv, float* __restrict__ out_msg, float* s_red, int cofs)
{
    int t = threadIdx.x;
    int w = t >> 6, l = t & 63;
    int lrow = l & 15, q = l >> 4;
    int nt0 = w * 2, nt1 = nt0 + 1;
    v4f a00 = {0.f,0.f,0.f,0.f}, a01 = {0.f,0.f,0.f,0.f};
    v4f a10 = {0.f,0.f,0.f,0.f}, a11 = {0.f,0.f,0.f,0.f};
#pragma unroll
    for (int kt = 0; kt < 8; ++kt) {
        v8s b0 = *(const v8s*)&wpack[(size_t)(nt0 * 8 + kt) * 512 + l * 8];
        v8s b1 = *(const v8s*)&wpack[(size_t)(nt1 * 8 + kt) * 512 + l * 8];
        v8s x0 = *(const v8s*)&srcLDS[lrow * H_STRIDE + kt * 32 + q * 8];
        v8s x1 = *(const v8s*)&srcLDS[(16 + lrow) * H_STRIDE + kt * 32 + q * 8];
        a00 = MFMA(x0, b0, a00, 0, 0, 0);
        a01 = MFMA(x0, b1, a01, 0, 0, 0);
        a10 = MFMA(x1, b0, a10, 0, 0, 0);
        a11 = MFMA(x1, b1, a11, 0, 0, 0);
    }
    int col0 = nt0 * 16 + lrow, col1 = col0 + 16;
#pragma unroll
    for (int r = 0; r < 4; ++r) {
        int row0 = q * 4 + r, row1 = row0 + 16;
        s_red[row0 * RED_S + col0] = a00[r] * OUT_SCALE;
        s_red[row0 * RED_S + col1] = a01[r] * OUT_SCALE;
        s_red[row1 * RED_S + col0] = a10[r] * OUT_SCALE;
        s_red[row1 * RED_S + col1] = a11[r] * OUT_SCALE;
    }
    __syncthreads();
    reduce_plane(s_red, s_rcv, out_msg, cofs);
}

// ---------------------------------------------------------------------------
// Edge-parallel fused kernel: EB=32, 4 waves, dual m-tile, RECEIVER-SORTED.
// Output: in-LDS segment reduction (stride RED_S) + fp32 atomic partials.
// s_red aliases s_hA (32*RED_S*4 = 16640 <= 16896 B).
// __launch_bounds__(256,3): VGPR budget ~85, no spill.
// ---------------------------------------------------------------------------
__global__ __launch_bounds__(256, 3) void edge_msg_kernel(
    const int* __restrict__ eidx, const int* __restrict__ esort,
    const float* __restrict__ ef, const float* __restrict__ ea,
    const ushort* __restrict__ down,
    const ushort* __restrict__ u0, const ushort* __restrict__ u1,
    const ushort* __restrict__ w1p, const ushort* __restrict__ w2p,
    const ushort* __restrict__ w3p, const ushort* __restrict__ w4p,
    const ushort* __restrict__ wl0p, const ushort* __restrict__ wl1p,
    float* __restrict__ out_msg)
{
    __shared__ __align__(16) ushort s_hA[EB * H_STRIDE];
    __shared__ __align__(16) ushort s_hB[EB * H_STRIDE];
    __shared__ __align__(16) ushort s_q[EB * H_STRIDE];   // q1 [0,128), q2 [128,256)
    __shared__ int s_snd[EB];
    __shared__ int s_rcv[EB];
    __shared__ int s_eid[EB];
    __shared__ float s_y[EB][4];

    float* s_red = (float*)s_hA;   // 32xRED_S fp32 reduction tile (aliases s_hA)

    int t = threadIdx.x;
    int e0 = blockIdx.x * EB;

    if (t < EB) {
        int e = esort[e0 + t];
        if (e < 0) e = 0; if (e >= N_EDGES) e = N_EDGES - 1;
        s_eid[t] = e;
        int s = eidx[e];
        int r = eidx[N_EDGES + e];
        if (s < 0) s = 0; if (s >= N_NODES) s = N_NODES - 1;
        if (r < 0) r = 0; if (r >= N_NODES) r = N_NODES - 1;
        s_snd[t] = s; s_rcv[t] = r;
        s_y[t][0] = fin(ea[(size_t)e * 4 + 0]);
        s_y[t][1] = fin(ea[(size_t)e * 4 + 1]);
        s_y[t][2] = fin(ea[(size_t)e * 4 + 2]);
        s_y[t][3] = fin(ea[(size_t)e * 4 + 3]);
    }
    __syncthreads();
    // stage aug into s_hB stride 168 — 8 threads/edge, 21 cols each (8*21=168)
    {
        int e = t >> 3, c0 = (t & 7) * 21;
        int snd = s_snd[e], rcv = s_rcv[e], eid = s_eid[e];
#pragma unroll
        for (int j = 0; j < 21; ++j) {
            int cc = c0 + j;
            ushort vv;
            if (cc < 8)        vv = f2bf(ef[(size_t)eid * 8 + cc]);
            else if (cc < 72)  vv = down[(size_t)snd * 64 + (cc - 8)];
            else if (cc < 136) vv = down[(size_t)rcv * 64 + (cc - 72)];
            else               vv = 0;
            s_hB[e * 168 + cc] = vv;
        }
    }
    __syncthreads();
    gemm_layer<5, true>(w1p, s_hB, 168, s_hA, S_MLP1);       // aug -> hA
    gemm_layer<8, true>(w2p, s_hA, H_STRIDE, s_hB, S_MLP);   // hA  -> hB
    gemm_layer<8, true>(w3p, s_hB, H_STRIDE, s_hA, S_MLP);   // hB  -> hA

    // ---- layer 4 quarters (dual-m, in-loop A reads from hA) ----
    int w = t >> 6, l = t & 63;
    int lrow = l & 15, q = l >> 4;
    int colg0 = w * 32 + lrow, colg1 = colg0 + 16;

    for (int qd = 0; qd < 4; ++qd) {
        int nt0 = qd * 8 + w * 2, nt1 = nt0 + 1;
        v4f a00 = {0.f,0.f,0.f,0.f}, a01 = {0.f,0.f,0.f,0.f};
        v4f a10 = {0.f,0.f,0.f,0.f}, a11 = {0.f,0.f,0.f,0.f};
#pragma unroll
        for (int kt = 0; kt < 8; ++kt) {
            v8s b0 = *(const v8s*)&w4p[(size_t)(nt0 * 8 + kt) * 512 + l * 8];
            v8s b1 = *(const v8s*)&w4p[(size_t)(nt1 * 8 + kt) * 512 + l * 8];
            v8s x0 = *(const v8s*)&s_hA[lrow * H_STRIDE + kt * 32 + q * 8];
            v8s x1 = *(const v8s*)&s_hA[(16 + lrow) * H_STRIDE + kt * 32 + q * 8];
            a00 = MFMA(x0, b0, a00, 0, 0, 0);
            a01 = MFMA(x0, b1, a01, 0, 0, 0);
            a10 = MFMA(x1, b0, a10, 0, 0, 0);
            a11 = MFMA(x1, b1, a11, 0, 0, 0);
        }
#pragma unroll
        for (int r = 0; r < 4; ++r) {
#pragma unroll
            for (int m = 0; m < 2; ++m) {
                int row = m * 16 + q * 4 + r;
                float v0 = (m == 0 ? a00[r] : a10[r]) * S_MLP;
                float v1 = (m == 0 ? a01[r] : a11[r]) * S_MLP;
                int snd = s_snd[row];
                if (qd == 0) {
                    float y0 = s_y[row][0];
                    float ua = bf2f(u0[(size_t)snd * 128 + colg0]);
                    float ub = bf2f(u0[(size_t)snd * 128 + colg1]);
                    unsigned pk = cvt_pk_bf16(v0 * ua * y0, v1 * ub * y0);
                    s_hB[row * H_STRIDE + colg0] = (ushort)pk;
                    s_hB[row * H_STRIDE + colg1] = (ushort)(pk >> 16);
                } else if (qd == 1) {
                    float ua = bf2f(u0[(size_t)snd * 128 + colg0]);
                    float ub = bf2f(u0[(size_t)snd * 128 + colg1]);
                    unsigned pk = cvt_pk_bf16(v0 * ua, v1 * ub);
                    s_q[row * H_STRIDE + colg0] = (ushort)pk;
                    s_q[row * H_STRIDE + colg1] = (ushort)(pk >> 16);
                } else if (qd == 2) {
                    unsigned pk = cvt_pk_bf16(v0, v1);
                    s_q[row * H_STRIDE + 128 + colg0] = (ushort)pk;
                    s_q[row * H_STRIDE + 128 + colg1] = (ushort)(pk >> 16);
                } else {
                    size_t ub_ = (size_t)snd * 384;
                    float d0 = bf2f(u1[ub_ + colg0])       * s_y[row][1]
                             + bf2f(u1[ub_ + 128 + colg0]) * s_y[row][2]
                             + bf2f(u1[ub_ + 256 + colg0]) * s_y[row][3];
                    float d1 = bf2f(u1[ub_ + colg1])       * s_y[row][1]
                             + bf2f(u1[ub_ + 128 + colg1]) * s_y[row][2]
                             + bf2f(u1[ub_ + 256 + colg1]) * s_y[row][3];
                    unsigned pk = cvt_pk_bf16(v0 * d0 * INV_SQRT3, v1 * d1 * INV_SQRT3);
                    s_hB[row * H_STRIDE + 128 + colg0] = (ushort)pk;
                    s_hB[row * H_STRIDE + 128 + colg1] = (ushort)(pk >> 16);
                }
            }
        }
    }
    __syncthreads();   // layer-4 done; s_hA becomes s_red from here on

    gemm_out(wl0p, s_hB, s_rcv, out_msg, s_red, 0);
    __syncthreads();   // s_red reads done before next plane overwrites

    // ---- wl1 with Z-factorization (dual-m) ----
    const ushort* wl1t = wl1p;            // rows [0,128)  of W_lin1, KT=4
    const ushort* wl1b = wl1p + 16384;    // rows [128,256) of W_lin1, KT=4
    int ntz0 = w * 2, ntz1 = ntz0 + 1;

    // Z = q1 @ wl1_top, held in regs across the i-loop
    v4f z00 = {0.f,0.f,0.f,0.f}, z01 = {0.f,0.f,0.f,0.f};
    v4f z10 = {0.f,0.f,0.f,0.f}, z11 = {0.f,0.f,0.f,0.f};
#pragma unroll
    for (int kt = 0; kt < 4; ++kt) {
        v8s b0 = *(const v8s*)&wl1t[(size_t)(ntz0 * 4 + kt) * 512 + l * 8];
        v8s b1 = *(const v8s*)&wl1t[(size_t)(ntz1 * 4 + kt) * 512 + l * 8];
        v8s x0 = *(const v8s*)&s_q[lrow * H_STRIDE + kt * 32 + q * 8];
        v8s x1 = *(const v8s*)&s_q[(16 + lrow) * H_STRIDE + kt * 32 + q * 8];
        z00 = MFMA(x0, b0, z00, 0, 0, 0);
        z01 = MFMA(x0, b1, z01, 0, 0, 0);
        z10 = MFMA(x1, b0, z10, 0, 0, 0);
        z11 = MFMA(x1, b1, z11, 0, 0, 0);
    }

    int colz0 = ntz0 * 16 + lrow, colz1 = colz0 + 16;
    for (int i = 0; i < 3; ++i) {
        // rebuild q2*u1_i*y0 into s_hB cols [0,128), 2-wide packed
#pragma unroll
        for (int it = 0; it < 8; ++it) {
            int idx = t + it * 256;
            int e = idx >> 6, kp = (idx & 63) << 1;
            unsigned uq = *(const unsigned*)&s_q[e * H_STRIDE + 128 + kp];
            unsigned uu = *(const unsigned*)&u1[(size_t)s_snd[e] * 384 + i * 128 + kp];
            float y0 = s_y[e][0];
            float lo = bf2f((ushort)uq) * bf2f((ushort)uu) * y0;
            float hi = bf2f((ushort)(uq >> 16)) * bf2f((ushort)(uu >> 16)) * y0;
            *(unsigned*)&s_hB[e * H_STRIDE + kp] = cvt_pk_bf16(lo, hi);
        }
        __syncthreads();
        // P_i = rebuilt @ wl1_bot; out = y_{1+i}*Z + P_i -> s_red -> reduce
        v4f p00 = {0.f,0.f,0.f,0.f}, p01 = {0.f,0.f,0.f,0.f};
        v4f p10 = {0.f,0.f,0.f,0.f}, p11 = {0.f,0.f,0.f,0.f};
#pragma unroll
        for (int kt = 0; kt < 4; ++kt) {
            v8s b0 = *(const v8s*)&wl1b[(size_t)(ntz0 * 4 + kt) * 512 + l * 8];
            v8s b1 = *(const v8s*)&wl1b[(size_t)(ntz1 * 4 + kt) * 512 + l * 8];
            v8s x0 = *(const v8s*)&s_hB[lrow * H_STRIDE + kt * 32 + q * 8];
            v8s x1 = *(const v8s*)&s_hB[(16 + lrow) * H_STRIDE + kt * 32 + q * 8];
            p00 = MFMA(x0, b0, p00, 0, 0, 0);
            p01 = MFMA(x0, b1, p01, 0, 0, 0);
            p10 = MFMA(x1, b0, p10, 0, 0, 0);
            p11 = MFMA(x1, b1, p11, 0, 0, 0);
        }
#pragma unroll
        for (int r = 0; r < 4; ++r) {
            int row0 = q * 4 + r, row1 = row0 + 16;
            float yi0 = s_y[row0][1 + i], yi1 = s_y[row1][1 + i];
            s_red[row0 * RED_S + colz0] = (yi0 * z00[r] + p00[r]) * OUT_SCALE;
            s_red[row0 * RED_S + colz1] = (yi0 * z01[r] + p01[r]) * OUT_SCALE;
            s_red[row1 * RED_S + colz0] = (yi1 * z10[r] + p10[r]) * OUT_SCALE;
            s_red[row1 * RED_S + colz1] = (yi1 * z11[r] + p11[r]) * OUT_SCALE;
        }
        __syncthreads();
        reduce_plane(s_red, s_rcv, out_msg, 1 + i);
        __syncthreads();   // s_red / s_hB safe for next iteration
    }
}

// ---------------------------------------------------------------------------
extern "C" void kernel_launch(void* const* d_in, const int* in_sizes, int n_in,
                              void* d_out, int out_size, void* d_ws, size_t ws_size,
                              hipStream_t stream)
{
    const float* node_feats = (const float*)d_in[1];
    const float* edge_attrs = (const float*)d_in[2];
    const float* edge_feats = (const float*)d_in[3];
    const int*   edge_index = (const int*)d_in[4];
    const float* W_up0  = (const float*)d_in[5];
    const float* W_up1  = (const float*)d_in[6];
    const float* W_down = (const float*)d_in[7];
    const float* mlp_w1 = (const float*)d_in[8];
    const float* mlp_w2 = (const float*)d_in[9];
    const float* mlp_w3 = (const float*)d_in[10];
    const float* mlp_w4 = (const float*)d_in[11];
    const float* W_lin0 = (const float*)d_in[12];
    const float* W_lin1 = (const float*)d_in[13];
    const float* W_skip0 = (const float*)d_in[14];
    const float* W_skip1 = (const float*)d_in[15];

    // d_out fp32: [message: 20,480,000 B][sc: 20,480,000 B]
    char* S = (char*)d_out + 20480000;   // sc half = scratch until node_sc

    ushort* u0    = (ushort*)(S + 0);           //  2,560,000 B
    ushort* down  = (ushort*)(S + 2560000);     //  1,280,000 B
    ushort* u1    = (ushort*)(S + 3840000);     //  7,680,000 B (planar [n][i][128])
    ushort* w1p   = (ushort*)(S + 11520000);    //     81,920 B
    ushort* w2p   = (ushort*)(S + 11601920);    //    131,072 B
    ushort* w3p   = (ushort*)(S + 11732992);    //    131,072 B
    ushort* w4p   = (ushort*)(S + 11864064);    //    262,144 B
    ushort* wl0p  = (ushort*)(S + 12126208);    //     65,536 B
    ushort* wl1p  = (ushort*)(S + 12191744);    //     65,536 B (top 32K + bottom 32K)
    int*    offs  = (int*)(S + 12257280);       //     40,032 B
    int*    esort = (int*)(S + 12297312);       //    640,000 B
    int*    counts= (int*)(S + 12937312);       //     40,000 B
    int*    cnt2  = (int*)(S + 12977312);       //     40,000 B -> 13,017,312

    float* out_msg = (float*)d_out;
    float* out_sc  = (float*)d_out + (size_t)N_NODES * 512;

    pack_kernel<<<1440, 256, 0, stream>>>(mlp_w1, mlp_w2, mlp_w3, mlp_w4, W_lin0, W_lin1,
                                          w1p, w2p, w3p, w4p, wl0p, wl1p);
    node_uud_kernel<<<N_NODES / NB, 256, 0, stream>>>(node_feats, W_up0, W_up1, W_down, u0, u1, down);

    hipMemsetAsync(counts, 0, 80000, stream);
    hipMemsetAsync(out_msg, 0, 20480000, stream);
    hist_kernel<<<N_EDGES / 256, 256, 0, stream>>>(edge_index, counts);
    scan_kernel<<<1, 1024, 0, stream>>>(counts, offs);
    fill_kernel<<<N_EDGES / 256, 256, 0, stream>>>(edge_index, offs, cnt2, esort);

    edge_msg_kernel<<<N_EDGES / EB, 256, 0, stream>>>(edge_index, esort,
        edge_feats, edge_attrs,
        down, u0, u1, w1p, w2p, w3p, w4p, wl0p, wl1p, out_msg);

    node_sc_kernel<<<N_NODES / NB, 256, 0, stream>>>(node_feats, W_skip0, W_skip1, out_sc);
}